// Round 2
// baseline (9565.807 us; speedup 1.0000x reference)
//
#include <hip/hip_runtime.h>
#include <hip/hip_bf16.h>
#include <stdint.h>

typedef unsigned short u16;
typedef unsigned int u32;
typedef short s16x8 __attribute__((ext_vector_type(8)));
typedef float f32x4 __attribute__((ext_vector_type(4)));

#define NN 50000
#define EE 800000
#define BB 64
#define PP 3

__device__ __forceinline__ float b2f(u16 x){ union{u32 u; float f;} c; c.u=((u32)x)<<16; return c.f; }
__device__ __forceinline__ u16 f2b(float v){ union{float f; u32 u;} c; c.f=v; u32 u=c.u; return (u16)((u + 0x7fffu + ((u>>16)&1u))>>16); }
__device__ __forceinline__ float lrelu(float v){ return v>0.f ? v : 0.01f*v; }
__device__ __forceinline__ f32x4 MFMA(s16x8 a, s16x8 b, f32x4 c){
  return __builtin_amdgcn_mfma_f32_16x16x32_bf16(a,b,c,0,0,0);
}

// ---------------- weight repack: fp32 [P][K][N] row-major -> bf16 per-lane MFMA B fragments
// frag element (p, kb, nb, lane, j) = W[p][kb*32 + (lane>>4)*8 + j][nb*16 + (lane&15)]
__global__ __launch_bounds__(256) void k_repack(const float* __restrict__ W, u16* __restrict__ out, int K, int Nn){
  int chunks_pp = (K/32)*(Nn/16)*64;
  int t = blockIdx.x*256 + threadIdx.x;
  if (t >= PP*chunks_pp) return;
  int p = t/chunks_pp, rem = t%chunks_pp;
  int NB = Nn/16;
  int kb = rem/(NB*64); int r2 = rem%(NB*64);
  int nb = r2/64; int l = r2&63;
  const float* Wp = W + (size_t)p*K*Nn;
  int k0 = kb*32 + ((l>>4)<<3), n = nb*16 + (l&15);
  u16 tmp[8];
  #pragma unroll
  for (int j=0;j<8;j++) tmp[j] = f2b(Wp[(size_t)(k0+j)*Nn + n]);
  *(uint4*)(out + (size_t)t*8) = *(uint4*)tmp;
}

// ---------------- embeddings: out[row] = lrelu(in[row,0:16] @ W[16,64] + b)  (fp32 in -> bf16 out)
__global__ __launch_bounds__(256) void k_embed(const float* __restrict__ in, const float* __restrict__ W,
                                               const float* __restrict__ b, u16* __restrict__ out, int nrows){
  __shared__ float wl[1024];
  __shared__ float bl[64];
  int tid = threadIdx.x;
  for (int i=tid;i<1024;i+=256) wl[i]=W[i];
  if (tid<64) bl[tid]=b[tid];
  __syncthreads();
  int row = blockIdx.x*256 + tid;
  if (row >= nrows) return;
  float inb[16];
  const float4* src4=(const float4*)(in + (size_t)row*16);
  #pragma unroll
  for (int q=0;q<4;q++){ float4 v=src4[q]; inb[q*4]=v.x; inb[q*4+1]=v.y; inb[q*4+2]=v.z; inb[q*4+3]=v.w; }
  float acc[64];
  #pragma unroll
  for (int j=0;j<64;j++) acc[j]=bl[j];
  #pragma unroll
  for (int k=0;k<16;k++){
    float a = inb[k];
    const float4* wr4 = (const float4*)(wl + k*64);
    #pragma unroll
    for (int j4=0;j4<16;j4++){
      float4 w4 = wr4[j4];
      acc[j4*4+0] += a*w4.x; acc[j4*4+1] += a*w4.y;
      acc[j4*4+2] += a*w4.z; acc[j4*4+3] += a*w4.w;
    }
  }
  u16 ob[64];
  #pragma unroll
  for (int j=0;j<64;j++) ob[j]=f2b(lrelu(acc[j]));
  uint4* dst=(uint4*)(out + (size_t)row*64);
  #pragma unroll
  for (int j=0;j<8;j++) dst[j]=((uint4*)ob)[j];
}

__global__ void k_embed_g(const float* __restrict__ in, const float* __restrict__ W, const float* __restrict__ b,
                          u16* __restrict__ g_b, float* __restrict__ g_f){
  __shared__ float wl[1024];
  __shared__ float bl[64];
  int tid = threadIdx.x; // 64 threads
  for (int i=tid;i<1024;i+=64) wl[i]=W[i];
  if (tid<64) bl[tid]=b[tid];
  __syncthreads();
  int row = tid;
  float inb[16];
  const float4* src4=(const float4*)(in + (size_t)row*16);
  #pragma unroll
  for (int q=0;q<4;q++){ float4 v=src4[q]; inb[q*4]=v.x; inb[q*4+1]=v.y; inb[q*4+2]=v.z; inb[q*4+3]=v.w; }
  float acc[64];
  #pragma unroll
  for (int j=0;j<64;j++) acc[j]=bl[j];
  #pragma unroll
  for (int k=0;k<16;k++){
    float a = inb[k];
    const float* wr = wl + k*64;
    #pragma unroll
    for (int j=0;j<64;j++) acc[j] += a*wr[j];
  }
  #pragma unroll
  for (int j=0;j<64;j++){
    float v = lrelu(acc[j]);
    g_f[row*64+j] = v;
    g_b[row*64+j] = f2b(v);
  }
}

// RMW helper: 16 contiguous bf16 += vals
__device__ __forceinline__ void rmw16(u16* p, const float* vals){
  uint4 q0=((uint4*)p)[0], q1=((uint4*)p)[1];
  const u16* h0=(const u16*)&q0; const u16* hq=(const u16*)&q1;
  u16 o[16];
  #pragma unroll
  for (int c=0;c<8;c++) o[c]=f2b(b2f(h0[c])+vals[c]);
  #pragma unroll
  for (int c=0;c<8;c++) o[8+c]=f2b(b2f(hq[c])+vals[8+c]);
  ((uint4*)p)[0]=*(uint4*)o; ((uint4*)p)[1]=*(uint4*)(o+8);
}

// ---------------- fused 3-layer MLP per 64 rows.
// MODE 0: edge model, MODE 1: node model, MODE 2: global model.
template<int K0, int MODE>
__global__ __launch_bounds__(256) void k_mlp(
    u16* __restrict__ xh_b, u16* __restrict__ e_b,
    float* __restrict__ eagg, float* __restrict__ xagg,
    u16* __restrict__ g_b, float* __restrict__ g_f,
    const int* __restrict__ eidx, const int* __restrict__ batch,
    const uint4* __restrict__ w1f, const uint4* __restrict__ w2f, const uint4* __restrict__ w3f,
    const float* __restrict__ b1, const float* __restrict__ b2, const float* __restrict__ b3)
{
  constexpr int KB  = K0/32;
  constexpr int HKB = KB/2;
  constexpr int RS  = K0*2;   // a0 row stride bytes
  __shared__ __align__(16) char a0[64*RS];
  __shared__ __align__(16) char h1[16384];
  __shared__ __align__(16) char wbuf[32768];

  const int tid  = threadIdx.x;
  const int wave = tid>>6, lane = tid&63;
  const int rowbase = blockIdx.x*64;

  // ---------- gather input rows into swizzled a0 ----------
  {
    const int r = tid>>2, s = tid&3;
    char* drow = a0 + r*RS;
    const int sw = (r&7)<<4;
    if (MODE==0){
      const size_t edge = (size_t)rowbase + r;
      const int er = eidx[edge], ec = eidx[EE+edge];
      const u16* src = (s==0)? xh_b + (size_t)er*64
                     : (s==1)? xh_b + (size_t)ec*64
                     : (s==2)? e_b  + edge*64
                     :         g_b  + (size_t)batch[er]*64;
      const uint4* s4=(const uint4*)src;
      #pragma unroll
      for (int j=0;j<8;j++)
        *(uint4*)(drow + ((s*128 + j*16) ^ sw)) = s4[j];
    } else if (MODE==1){
      const int node = rowbase + r;
      const bool ok = node < NN;
      if (s==0){
        const uint4* s4=(const uint4*)(xh_b + (size_t)node*64);
        #pragma unroll
        for (int j=0;j<8;j++){ uint4 v={0,0,0,0}; if (ok) v=s4[j];
          *(uint4*)(drow + ((j*16) ^ sw)) = v; }
      } else if (s==1){
        const float4* s4=(const float4*)(eagg + (size_t)node*64);
        #pragma unroll
        for (int j=0;j<8;j++){
          u16 tmp[8]={0,0,0,0,0,0,0,0};
          if (ok){ float4 lo=s4[2*j], hi=s4[2*j+1];
            tmp[0]=f2b(lo.x);tmp[1]=f2b(lo.y);tmp[2]=f2b(lo.z);tmp[3]=f2b(lo.w);
            tmp[4]=f2b(hi.x);tmp[5]=f2b(hi.y);tmp[6]=f2b(hi.z);tmp[7]=f2b(hi.w); }
          *(uint4*)(drow + ((128 + j*16) ^ sw)) = *(uint4*)tmp;
        }
      } else if (s==2){
        int bidx = ok ? batch[node] : 0;
        const uint4* s4=(const uint4*)(g_b + (size_t)bidx*64);
        #pragma unroll
        for (int j=0;j<8;j++){ uint4 v={0,0,0,0}; if (ok) v=s4[j];
          *(uint4*)(drow + ((256 + j*16) ^ sw)) = v; }
      }
    } else { // GLOB: 64 graphs, all valid
      if (s==0){
        const uint4* s4=(const uint4*)(g_b + (size_t)r*64);
        #pragma unroll
        for (int j=0;j<8;j++) *(uint4*)(drow + ((j*16) ^ sw)) = s4[j];
      } else if (s==1){
        const float4* s4=(const float4*)(xagg + (size_t)r*64);
        #pragma unroll
        for (int j=0;j<8;j++){
          u16 tmp[8];
          float4 lo=s4[2*j], hi=s4[2*j+1];
          tmp[0]=f2b(lo.x);tmp[1]=f2b(lo.y);tmp[2]=f2b(lo.z);tmp[3]=f2b(lo.w);
          tmp[4]=f2b(hi.x);tmp[5]=f2b(hi.y);tmp[6]=f2b(hi.z);tmp[7]=f2b(hi.w);
          *(uint4*)(drow + ((128 + j*16) ^ sw)) = *(uint4*)tmp;
        }
      }
    }
  }
  // stage W1 half 0
  for (int i=tid;i<HKB*8*64;i+=256) ((uint4*)wbuf)[i]=w1f[i];
  __syncthreads();

  const int arow = wave*16 + (lane&15);
  const int asw  = (arow&7)<<4;
  const int aoff = (lane>>4)*16;

  f32x4 acc[8];
  #pragma unroll
  for (int nb=0;nb<8;nb++) acc[nb]=f32x4{0.f,0.f,0.f,0.f};

  // ---------- layer 1 (K0 -> 128) in two K-halves ----------
  #pragma unroll
  for (int half=0; half<2; ++half){
    if (half){
      __syncthreads();
      for (int i=tid;i<HKB*8*64;i+=256) ((uint4*)wbuf)[i]=w1f[HKB*8*64 + i];
      __syncthreads();
    }
    for (int kb2=0; kb2<HKB; ++kb2){
      const int kb = half*HKB + kb2;
      s16x8 af = *(const s16x8*)(a0 + arow*RS + ((kb*64 + aoff) ^ asw));
      #pragma unroll
      for (int nb=0;nb<8;nb++){
        s16x8 bfr = ((const s16x8*)wbuf)[(kb2*8+nb)*64 + lane];
        acc[nb] = MFMA(af,bfr,acc[nb]);
      }
    }
  }
  __syncthreads();
  // epilogue 1 -> h1 (bf16, swizzled 256B rows) ; stage W2
  #pragma unroll
  for (int nb=0;nb<8;nb++){
    int col = nb*16 + (lane&15);
    float bias = b1[col];
    #pragma unroll
    for (int r=0;r<4;r++){
      int orow = wave*16 + ((lane>>4)<<2) + r;
      *(u16*)(h1 + orow*256 + ((col*2) ^ ((orow&7)<<4))) = f2b(lrelu(acc[nb][r] + bias));
    }
  }
  for (int i=tid;i<2048;i+=256) ((uint4*)wbuf)[i]=w2f[i];
  __syncthreads();

  // ---------- layer 2 (128 -> 128) ----------
  #pragma unroll
  for (int nb=0;nb<8;nb++) acc[nb]=f32x4{0.f,0.f,0.f,0.f};
  for (int kb=0;kb<4;kb++){
    s16x8 af = *(const s16x8*)(h1 + arow*256 + ((kb*64 + aoff) ^ asw));
    #pragma unroll
    for (int nb=0;nb<8;nb++){
      s16x8 bfr = ((const s16x8*)wbuf)[(kb*8+nb)*64 + lane];
      acc[nb] = MFMA(af,bfr,acc[nb]);
    }
  }
  __syncthreads();
  // epilogue 2 -> h2 (reuse a0 region, bf16 256B rows) ; stage W3
  char* h2 = a0;
  #pragma unroll
  for (int nb=0;nb<8;nb++){
    int col = nb*16 + (lane&15);
    float bias = b2[col];
    #pragma unroll
    for (int r=0;r<4;r++){
      int orow = wave*16 + ((lane>>4)<<2) + r;
      *(u16*)(h2 + orow*256 + ((col*2) ^ ((orow&7)<<4))) = f2b(lrelu(acc[nb][r] + bias));
    }
  }
  for (int i=tid;i<1024;i+=256) ((uint4*)wbuf)[i]=w3f[i];
  __syncthreads();

  // ---------- layer 3 (128 -> 64, no activation) ----------
  f32x4 acc3[4];
  #pragma unroll
  for (int nb=0;nb<4;nb++) acc3[nb]=f32x4{0.f,0.f,0.f,0.f};
  for (int kb=0;kb<4;kb++){
    s16x8 af = *(const s16x8*)(h2 + arow*256 + ((kb*64 + aoff) ^ asw));
    #pragma unroll
    for (int nb=0;nb<4;nb++){
      s16x8 bfr = ((const s16x8*)wbuf)[(kb*4+nb)*64 + lane];
      acc3[nb] = MFMA(af,bfr,acc3[nb]);
    }
  }
  // epilogue 3: stage fp32 output into h1 region (h1 free after layer 2)
  #pragma unroll
  for (int nb=0;nb<4;nb++){
    int col = nb*16 + (lane&15);
    float bias = b3[col];
    #pragma unroll
    for (int r=0;r<4;r++){
      int orow = wave*16 + ((lane>>4)<<2) + r;
      *(float*)(h1 + orow*256 + ((col*4) ^ ((orow&7)<<4))) = acc3[nb][r] + bias;
    }
  }
  __syncthreads();

  // ---------- finisher ----------
  const int r2 = tid>>2, cs = (tid&3)*16;
  const int rsw2 = (r2&7)<<4;
  if (MODE==0){
    const size_t edge = (size_t)rowbase + r2;
    const int dcol = eidx[EE+edge];
    float vals[16];
    #pragma unroll
    for (int c=0;c<16;c++) vals[c]=*(const float*)(h1 + r2*256 + (((cs+c)*4)^rsw2));
    rmw16(e_b + edge*64 + cs, vals);       // e += e_new
    float* ar = eagg + (size_t)dcol*64 + cs;
    #pragma unroll
    for (int c=0;c<16;c++) unsafeAtomicAdd(ar+c, vals[c]);  // segment_sum(e_new, col)
  } else if (MODE==1){
    const int node = rowbase + r2;
    if (node < NN){
      float vals[16];
      #pragma unroll
      for (int c=0;c<16;c++) vals[c]=*(const float*)(h1 + r2*256 + (((cs+c)*4)^rsw2));
      rmw16(xh_b + (size_t)node*64 + cs, vals);             // xh += x_new
    }
    // per-graph reduction of x_new (batch sorted -> few runs per block)
    const int col = tid&63, rg = tid>>6;
    float s = 0.f; int cur = -1;
    for (int rr=0;rr<16;rr++){
      int row = rg*16+rr; int nd = rowbase+row;
      int gid = (nd<NN) ? batch[nd] : -1;
      float v = *(const float*)(h1 + row*256 + ((col*4) ^ ((row&7)<<4)));
      if (gid != cur){ if (cur>=0) unsafeAtomicAdd(xagg + cur*64 + col, s); s=0.f; cur=gid; }
      if (gid>=0) s += v;
    }
    if (cur>=0) unsafeAtomicAdd(xagg + cur*64 + col, s);
  } else {
    float vals[16];
    #pragma unroll
    for (int c=0;c<16;c++) vals[c]=*(const float*)(h1 + r2*256 + (((cs+c)*4)^rsw2));
    #pragma unroll
    for (int c=0;c<16;c++){
      int idx = r2*64 + cs + c;
      float nv = g_f[idx] + vals[c];
      g_f[idx] = nv; g_b[idx] = f2b(nv);     // g += g_new (fp32 master + bf16 copy)
    }
  }
}

// ---------------- edge decoder: out[e] = e_row . dec_w + dec_b  (fp32 out)
__global__ __launch_bounds__(256) void k_dec(const u16* __restrict__ e_b, const float* __restrict__ dec_w,
                                             const float* __restrict__ dec_b, float* __restrict__ out){
  __shared__ float wl[64];
  __shared__ float bsh;
  int tid=threadIdx.x;
  if (tid<64) wl[tid]=dec_w[tid];
  if (tid==0) bsh=dec_b[0];
  __syncthreads();
  size_t row = (size_t)blockIdx.x*256 + tid;
  if (row>=EE) return;
  const uint4* s4=(const uint4*)(e_b + row*64);
  float s=bsh;
  #pragma unroll
  for (int j=0;j<8;j++){
    uint4 q=s4[j];
    const u16* h=(const u16*)&q;
    #pragma unroll
    for (int t2=0;t2<8;t2++) s += b2f(h[t2])*wl[j*8+t2];
  }
  out[row]=s;
}

// ---------------- value head: lrelu(g @ vw1 + vb1) @ vw2 + vb2  (fp32 out)
__global__ void k_value(const float* __restrict__ g_f, const float* __restrict__ vw1, const float* __restrict__ vb1,
                        const float* __restrict__ vw2, const float* __restrict__ vb2, float* __restrict__ out){
  __shared__ float w1[4096];
  __shared__ float b1s[64];
  __shared__ float w2[64];
  int tid=threadIdx.x; // 64
  for (int i=tid;i<4096;i+=64) w1[i]=vw1[i];
  if (tid<64){ b1s[tid]=vb1[tid]; w2[tid]=vw2[tid]; }
  __syncthreads();
  float gi[64];
  #pragma unroll
  for (int k=0;k<64;k++) gi[k]=g_f[tid*64+k];
  float val=vb2[0];
  for (int j=0;j<64;j++){
    float s=b1s[j];
    #pragma unroll
    for (int k=0;k<64;k++) s+=gi[k]*w1[k*64+j];
    val += lrelu(s)*w2[j];
  }
  out[tid]=val;
}

extern "C" void kernel_launch(void* const* d_in, const int* in_sizes, int n_in,
                              void* d_out, int out_size, void* d_ws, size_t ws_size,
                              hipStream_t stream){
  const float* x    =(const float*)d_in[0];
  const float* ea   =(const float*)d_in[1];
  const float* uu   =(const float*)d_in[2];
  const float* eew  =(const float*)d_in[3];
  const float* eeb  =(const float*)d_in[4];
  const float* enw  =(const float*)d_in[5];
  const float* enb  =(const float*)d_in[6];
  const float* egw  =(const float*)d_in[7];
  const float* egb  =(const float*)d_in[8];
  const float* ew1  =(const float*)d_in[9];
  const float* eb1  =(const float*)d_in[10];
  const float* ew2  =(const float*)d_in[11];
  const float* eb2  =(const float*)d_in[12];
  const float* ew3  =(const float*)d_in[13];
  const float* eb3  =(const float*)d_in[14];
  const float* nw1  =(const float*)d_in[15];
  const float* nb1  =(const float*)d_in[16];
  const float* nw2  =(const float*)d_in[17];
  const float* nb2  =(const float*)d_in[18];
  const float* nw3  =(const float*)d_in[19];
  const float* nb3  =(const float*)d_in[20];
  const float* gw1  =(const float*)d_in[21];
  const float* gb1  =(const float*)d_in[22];
  const float* gw2  =(const float*)d_in[23];
  const float* gb2  =(const float*)d_in[24];
  const float* gw3  =(const float*)d_in[25];
  const float* gb3  =(const float*)d_in[26];
  const float* dw   =(const float*)d_in[27];
  const float* db   =(const float*)d_in[28];
  const float* vw1  =(const float*)d_in[29];
  const float* vb1  =(const float*)d_in[30];
  const float* vw2  =(const float*)d_in[31];
  const float* vb2  =(const float*)d_in[32];
  const int* eidx =(const int*)d_in[33];
  const int* batch=(const int*)d_in[34];

  char* ws=(char*)d_ws; size_t off=0;
  auto alloc=[&](size_t b)->char*{ char* p=ws+off; off=(off+b+255)&~(size_t)255; return p; };
  u16*   xh_b =(u16*)  alloc((size_t)NN*64*2);
  u16*   e_b  =(u16*)  alloc((size_t)EE*64*2);
  float* eagg =(float*)alloc((size_t)NN*64*4);
  float* xagg =(float*)alloc((size_t)BB*64*4);
  u16*   g_bb =(u16*)  alloc((size_t)BB*64*2);
  float* g_f  =(float*)alloc((size_t)BB*64*4);
  u16* ew1f=(u16*)alloc((size_t)PP*4096*16);
  u16* ew2f=(u16*)alloc((size_t)PP*2048*16);
  u16* ew3f=(u16*)alloc((size_t)PP*1024*16);
  u16* nw1f=(u16*)alloc((size_t)PP*3072*16);
  u16* nw2f=(u16*)alloc((size_t)PP*2048*16);
  u16* nw3f=(u16*)alloc((size_t)PP*1024*16);
  u16* gw1f=(u16*)alloc((size_t)PP*2048*16);
  u16* gw2f=(u16*)alloc((size_t)PP*2048*16);
  u16* gw3f=(u16*)alloc((size_t)PP*1024*16);
  float* out=(float*)d_out;

  auto rp=[&](const float* W, u16* dst, int K, int Nn){
    int total = PP*(K/32)*(Nn/16)*64;
    k_repack<<<(total+255)/256,256,0,stream>>>(W,dst,K,Nn);
  };
  rp(ew1,ew1f,256,128); rp(ew2,ew2f,128,128); rp(ew3,ew3f,128,64);
  rp(nw1,nw1f,192,128); rp(nw2,nw2f,128,128); rp(nw3,nw3f,128,64);
  rp(gw1,gw1f,128,128); rp(gw2,gw2f,128,128); rp(gw3,gw3f,128,64);

  k_embed<<<(EE+255)/256,256,0,stream>>>(ea, eew, eeb, e_b, EE);
  k_embed<<<(NN+255)/256,256,0,stream>>>(x,  enw, enb, xh_b, NN);
  k_embed_g<<<1,64,0,stream>>>(uu, egw, egb, g_bb, g_f);

  for (int p=0;p<PP;p++){
    hipMemsetAsync(eagg, 0, (size_t)NN*64*4, stream);
    hipMemsetAsync(xagg, 0, (size_t)BB*64*4, stream);
    k_mlp<256,0><<<EE/64,256,0,stream>>>(xh_b,e_b,eagg,xagg,g_bb,g_f,eidx,batch,
        (const uint4*)ew1f + (size_t)p*4096, (const uint4*)ew2f + (size_t)p*2048, (const uint4*)ew3f + (size_t)p*1024,
        eb1+p*128, eb2+p*128, eb3+p*64);
    k_mlp<192,1><<<(NN+63)/64,256,0,stream>>>(xh_b,e_b,eagg,xagg,g_bb,g_f,eidx,batch,
        (const uint4*)nw1f + (size_t)p*3072, (const uint4*)nw2f + (size_t)p*2048, (const uint4*)nw3f + (size_t)p*1024,
        nb1+p*128, nb2+p*128, nb3+p*64);
    k_mlp<128,2><<<1,256,0,stream>>>(xh_b,e_b,eagg,xagg,g_bb,g_f,eidx,batch,
        (const uint4*)gw1f + (size_t)p*2048, (const uint4*)gw2f + (size_t)p*2048, (const uint4*)gw3f + (size_t)p*1024,
        gb1+p*128, gb2+p*128, gb3+p*64);
  }
  k_dec<<<(EE+255)/256,256,0,stream>>>(e_b, dw, db, out);
  k_value<<<1,64,0,stream>>>(g_f, vw1, vb1, vw2, vb2, out+EE);
}

// Round 3
// 2160.170 us; speedup vs baseline: 4.4283x; 4.4283x over previous
//
#include <hip/hip_runtime.h>
#include <hip/hip_bf16.h>
#include <stdint.h>

typedef unsigned short u16;
typedef unsigned int u32;
typedef short s16x8 __attribute__((ext_vector_type(8)));
typedef float f32x4 __attribute__((ext_vector_type(4)));

#define NN 50000
#define EE 800000
#define BB 64
#define PP 3

__device__ __forceinline__ float b2f(u16 x){ union{u32 u; float f;} c; c.u=((u32)x)<<16; return c.f; }
__device__ __forceinline__ u16 f2b(float v){ union{float f; u32 u;} c; c.f=v; u32 u=c.u; return (u16)((u + 0x7fffu + ((u>>16)&1u))>>16); }
__device__ __forceinline__ float lrelu(float v){ return v>0.f ? v : 0.01f*v; }
__device__ __forceinline__ f32x4 MFMA(s16x8 a, s16x8 b, f32x4 c){
  return __builtin_amdgcn_mfma_f32_16x16x32_bf16(a,b,c,0,0,0);
}

// ---------------- counting sort of edges by destination ----------------
__global__ __launch_bounds__(256) void k_hist(const int* __restrict__ eidx, int* __restrict__ hist){
  int e = blockIdx.x*256 + threadIdx.x;
  if (e < EE) atomicAdd(&hist[eidx[EE+e]], 1);
}

__global__ __launch_bounds__(1024) void k_scan(const int* __restrict__ hist, int* __restrict__ offs){
  __shared__ int lsums[1024];
  const int tid = threadIdx.x;
  const int CH = 49; // 1024*49 = 50176 >= NN
  int base = tid*CH;
  int s = 0;
  for (int i=0;i<CH;i++){ int b=base+i; if (b<NN) s += hist[b]; }
  lsums[tid]=s; __syncthreads();
  for (int off=1; off<1024; off<<=1){
    int v = (tid>=off)? lsums[tid-off] : 0;
    __syncthreads();
    lsums[tid] += v;
    __syncthreads();
  }
  int run = (tid>0)? lsums[tid-1] : 0;
  for (int i=0;i<CH;i++){ int b=base+i; if (b<NN){ offs[b]=run; run+=hist[b]; } }
}

__global__ __launch_bounds__(256) void k_scatter(const int* __restrict__ eidx, int* __restrict__ offs,
                                                 int* __restrict__ perm, int* __restrict__ dcols){
  int e = blockIdx.x*256 + threadIdx.x;
  if (e >= EE) return;
  int col = eidx[EE+e];
  int pos = atomicAdd(&offs[col], 1);
  perm[pos] = e;
  dcols[pos] = col;
}

// ---------------- weight repack: fp32 [P][K][N] row-major -> bf16 per-lane MFMA B fragments
__global__ __launch_bounds__(256) void k_repack(const float* __restrict__ W, u16* __restrict__ out, int K, int Nn){
  int chunks_pp = (K/32)*(Nn/16)*64;
  int t = blockIdx.x*256 + threadIdx.x;
  if (t >= PP*chunks_pp) return;
  int p = t/chunks_pp, rem = t%chunks_pp;
  int NB = Nn/16;
  int kb = rem/(NB*64); int r2 = rem%(NB*64);
  int nb = r2/64; int l = r2&63;
  const float* Wp = W + (size_t)p*K*Nn;
  int k0 = kb*32 + ((l>>4)<<3), n = nb*16 + (l&15);
  u16 tmp[8];
  #pragma unroll
  for (int j=0;j<8;j++) tmp[j] = f2b(Wp[(size_t)(k0+j)*Nn + n]);
  *(uint4*)(out + (size_t)t*8) = *(uint4*)tmp;
}

// ---------------- embeddings: out[row] = lrelu(in[row,0:16] @ W[16,64] + b)  (fp32 in -> bf16 out)
__global__ __launch_bounds__(256) void k_embed(const float* __restrict__ in, const float* __restrict__ W,
                                               const float* __restrict__ b, u16* __restrict__ out, int nrows){
  __shared__ float wl[1024];
  __shared__ float bl[64];
  int tid = threadIdx.x;
  for (int i=tid;i<1024;i+=256) wl[i]=W[i];
  if (tid<64) bl[tid]=b[tid];
  __syncthreads();
  int row = blockIdx.x*256 + tid;
  if (row >= nrows) return;
  float inb[16];
  const float4* src4=(const float4*)(in + (size_t)row*16);
  #pragma unroll
  for (int q=0;q<4;q++){ float4 v=src4[q]; inb[q*4]=v.x; inb[q*4+1]=v.y; inb[q*4+2]=v.z; inb[q*4+3]=v.w; }
  float acc[64];
  #pragma unroll
  for (int j=0;j<64;j++) acc[j]=bl[j];
  #pragma unroll
  for (int k=0;k<16;k++){
    float a = inb[k];
    const float4* wr4 = (const float4*)(wl + k*64);
    #pragma unroll
    for (int j4=0;j4<16;j4++){
      float4 w4 = wr4[j4];
      acc[j4*4+0] += a*w4.x; acc[j4*4+1] += a*w4.y;
      acc[j4*4+2] += a*w4.z; acc[j4*4+3] += a*w4.w;
    }
  }
  u16 ob[64];
  #pragma unroll
  for (int j=0;j<64;j++) ob[j]=f2b(lrelu(acc[j]));
  uint4* dst=(uint4*)(out + (size_t)row*64);
  #pragma unroll
  for (int j=0;j<8;j++) dst[j]=((uint4*)ob)[j];
}

__global__ void k_embed_g(const float* __restrict__ in, const float* __restrict__ W, const float* __restrict__ b,
                          u16* __restrict__ g_b, float* __restrict__ g_f){
  __shared__ float wl[1024];
  __shared__ float bl[64];
  int tid = threadIdx.x; // 64 threads
  for (int i=tid;i<1024;i+=64) wl[i]=W[i];
  if (tid<64) bl[tid]=b[tid];
  __syncthreads();
  int row = tid;
  float inb[16];
  const float4* src4=(const float4*)(in + (size_t)row*16);
  #pragma unroll
  for (int q=0;q<4;q++){ float4 v=src4[q]; inb[q*4]=v.x; inb[q*4+1]=v.y; inb[q*4+2]=v.z; inb[q*4+3]=v.w; }
  float acc[64];
  #pragma unroll
  for (int j=0;j<64;j++) acc[j]=bl[j];
  #pragma unroll
  for (int k=0;k<16;k++){
    float a = inb[k];
    const float* wr = wl + k*64;
    #pragma unroll
    for (int j=0;j<64;j++) acc[j] += a*wr[j];
  }
  #pragma unroll
  for (int j=0;j<64;j++){
    float v = lrelu(acc[j]);
    g_f[row*64+j] = v;
    g_b[row*64+j] = f2b(v);
  }
}

// RMW helper: 16 contiguous bf16 += vals
__device__ __forceinline__ void rmw16(u16* p, const float* vals){
  uint4 q0=((uint4*)p)[0], q1=((uint4*)p)[1];
  const u16* h0=(const u16*)&q0; const u16* hq=(const u16*)&q1;
  u16 o[16];
  #pragma unroll
  for (int c=0;c<8;c++) o[c]=f2b(b2f(h0[c])+vals[c]);
  #pragma unroll
  for (int c=0;c<8;c++) o[8+c]=f2b(b2f(hq[c])+vals[8+c]);
  ((uint4*)p)[0]=*(uint4*)o; ((uint4*)p)[1]=*(uint4*)(o+8);
}

// ---------------- fused 3-layer MLP per 64 rows.
// MODE 0: edge model (dest-sorted slots), MODE 1: node model, MODE 2: global model.
template<int K0, int MODE>
__global__ __launch_bounds__(256) void k_mlp(
    u16* __restrict__ xh_b, u16* __restrict__ e_b,
    float* __restrict__ eagg, float* __restrict__ xagg,
    u16* __restrict__ g_b, float* __restrict__ g_f,
    const int* __restrict__ eidx, const int* __restrict__ batch,
    const int* __restrict__ perm, const int* __restrict__ dcols,
    const uint4* __restrict__ w1f, const uint4* __restrict__ w2f, const uint4* __restrict__ w3f,
    const float* __restrict__ b1, const float* __restrict__ b2, const float* __restrict__ b3)
{
  constexpr int KB  = K0/32;
  constexpr int HKB = KB/2;
  constexpr int RS  = K0*2;   // a0 row stride bytes
  __shared__ __align__(16) char a0[64*RS];
  __shared__ __align__(16) char h1[16384];
  __shared__ __align__(16) char wbuf[32768];
  __shared__ int s_edge[64];
  __shared__ int s_dcol[64];

  const int tid  = threadIdx.x;
  const int wave = tid>>6, lane = tid&63;
  const int rowbase = blockIdx.x*64;

  // ---------- gather input rows into swizzled a0 ----------
  {
    const int r = tid>>2, s = tid&3;
    char* drow = a0 + r*RS;
    const int sw = (r&7)<<4;
    if (MODE==0){
      const int slot = rowbase + r;
      const int edge = perm[slot];
      if (s==0){ s_edge[r]=edge; s_dcol[r]=dcols[slot]; }
      const int er = eidx[edge], ec = eidx[EE+edge];
      const u16* src = (s==0)? xh_b + (size_t)er*64
                     : (s==1)? xh_b + (size_t)ec*64
                     : (s==2)? e_b  + (size_t)edge*64
                     :         g_b  + (size_t)batch[er]*64;
      const uint4* s4=(const uint4*)src;
      #pragma unroll
      for (int j=0;j<8;j++)
        *(uint4*)(drow + ((s*128 + j*16) ^ sw)) = s4[j];
    } else if (MODE==1){
      const int node = rowbase + r;
      const bool ok = node < NN;
      if (s==0){
        const uint4* s4=(const uint4*)(xh_b + (size_t)node*64);
        #pragma unroll
        for (int j=0;j<8;j++){ uint4 v={0,0,0,0}; if (ok) v=s4[j];
          *(uint4*)(drow + ((j*16) ^ sw)) = v; }
      } else if (s==1){
        const float4* s4=(const float4*)(eagg + (size_t)node*64);
        #pragma unroll
        for (int j=0;j<8;j++){
          u16 tmp[8]={0,0,0,0,0,0,0,0};
          if (ok){ float4 lo=s4[2*j], hi=s4[2*j+1];
            tmp[0]=f2b(lo.x);tmp[1]=f2b(lo.y);tmp[2]=f2b(lo.z);tmp[3]=f2b(lo.w);
            tmp[4]=f2b(hi.x);tmp[5]=f2b(hi.y);tmp[6]=f2b(hi.z);tmp[7]=f2b(hi.w); }
          *(uint4*)(drow + ((128 + j*16) ^ sw)) = *(uint4*)tmp;
        }
      } else if (s==2){
        int bidx = ok ? batch[node] : 0;
        const uint4* s4=(const uint4*)(g_b + (size_t)bidx*64);
        #pragma unroll
        for (int j=0;j<8;j++){ uint4 v={0,0,0,0}; if (ok) v=s4[j];
          *(uint4*)(drow + ((256 + j*16) ^ sw)) = v; }
      }
    } else { // GLOB: 64 graphs, all valid
      if (s==0){
        const uint4* s4=(const uint4*)(g_b + (size_t)r*64);
        #pragma unroll
        for (int j=0;j<8;j++) *(uint4*)(drow + ((j*16) ^ sw)) = s4[j];
      } else if (s==1){
        const float4* s4=(const float4*)(xagg + (size_t)r*64);
        #pragma unroll
        for (int j=0;j<8;j++){
          u16 tmp[8];
          float4 lo=s4[2*j], hi=s4[2*j+1];
          tmp[0]=f2b(lo.x);tmp[1]=f2b(lo.y);tmp[2]=f2b(lo.z);tmp[3]=f2b(lo.w);
          tmp[4]=f2b(hi.x);tmp[5]=f2b(hi.y);tmp[6]=f2b(hi.z);tmp[7]=f2b(hi.w);
          *(uint4*)(drow + ((128 + j*16) ^ sw)) = *(uint4*)tmp;
        }
      }
    }
  }
  // stage W1 half 0
  for (int i=tid;i<HKB*8*64;i+=256) ((uint4*)wbuf)[i]=w1f[i];
  __syncthreads();

  const int arow = wave*16 + (lane&15);
  const int asw  = (arow&7)<<4;
  const int aoff = (lane>>4)*16;

  f32x4 acc[8];
  #pragma unroll
  for (int nb=0;nb<8;nb++) acc[nb]=f32x4{0.f,0.f,0.f,0.f};

  // ---------- layer 1 (K0 -> 128) in two K-halves ----------
  #pragma unroll
  for (int half=0; half<2; ++half){
    if (half){
      __syncthreads();
      for (int i=tid;i<HKB*8*64;i+=256) ((uint4*)wbuf)[i]=w1f[HKB*8*64 + i];
      __syncthreads();
    }
    for (int kb2=0; kb2<HKB; ++kb2){
      const int kb = half*HKB + kb2;
      s16x8 af = *(const s16x8*)(a0 + arow*RS + ((kb*64 + aoff) ^ asw));
      #pragma unroll
      for (int nb=0;nb<8;nb++){
        s16x8 bfr = ((const s16x8*)wbuf)[(kb2*8+nb)*64 + lane];
        acc[nb] = MFMA(af,bfr,acc[nb]);
      }
    }
  }
  __syncthreads();
  // epilogue 1 -> h1 (bf16, swizzled 256B rows) ; stage W2
  #pragma unroll
  for (int nb=0;nb<8;nb++){
    int col = nb*16 + (lane&15);
    float bias = b1[col];
    #pragma unroll
    for (int r=0;r<4;r++){
      int orow = wave*16 + ((lane>>4)<<2) + r;
      *(u16*)(h1 + orow*256 + ((col*2) ^ ((orow&7)<<4))) = f2b(lrelu(acc[nb][r] + bias));
    }
  }
  for (int i=tid;i<2048;i+=256) ((uint4*)wbuf)[i]=w2f[i];
  __syncthreads();

  // ---------- layer 2 (128 -> 128) ----------
  #pragma unroll
  for (int nb=0;nb<8;nb++) acc[nb]=f32x4{0.f,0.f,0.f,0.f};
  for (int kb=0;kb<4;kb++){
    s16x8 af = *(const s16x8*)(h1 + arow*256 + ((kb*64 + aoff) ^ asw));
    #pragma unroll
    for (int nb=0;nb<8;nb++){
      s16x8 bfr = ((const s16x8*)wbuf)[(kb*8+nb)*64 + lane];
      acc[nb] = MFMA(af,bfr,acc[nb]);
    }
  }
  __syncthreads();
  // epilogue 2 -> h2 (reuse a0 region, bf16 256B rows) ; stage W3
  char* h2 = a0;
  #pragma unroll
  for (int nb=0;nb<8;nb++){
    int col = nb*16 + (lane&15);
    float bias = b2[col];
    #pragma unroll
    for (int r=0;r<4;r++){
      int orow = wave*16 + ((lane>>4)<<2) + r;
      *(u16*)(h2 + orow*256 + ((col*2) ^ ((orow&7)<<4))) = f2b(lrelu(acc[nb][r] + bias));
    }
  }
  for (int i=tid;i<1024;i+=256) ((uint4*)wbuf)[i]=w3f[i];
  __syncthreads();

  // ---------- layer 3 (128 -> 64, no activation) ----------
  f32x4 acc3[4];
  #pragma unroll
  for (int nb=0;nb<4;nb++) acc3[nb]=f32x4{0.f,0.f,0.f,0.f};
  for (int kb=0;kb<4;kb++){
    s16x8 af = *(const s16x8*)(h2 + arow*256 + ((kb*64 + aoff) ^ asw));
    #pragma unroll
    for (int nb=0;nb<4;nb++){
      s16x8 bfr = ((const s16x8*)wbuf)[(kb*4+nb)*64 + lane];
      acc3[nb] = MFMA(af,bfr,acc3[nb]);
    }
  }
  // epilogue 3: stage fp32 output into h1 region (h1 free after layer 2)
  #pragma unroll
  for (int nb=0;nb<4;nb++){
    int col = nb*16 + (lane&15);
    float bias = b3[col];
    #pragma unroll
    for (int r=0;r<4;r++){
      int orow = wave*16 + ((lane>>4)<<2) + r;
      *(float*)(h1 + orow*256 + ((col*4) ^ ((orow&7)<<4))) = acc3[nb][r] + bias;
    }
  }
  __syncthreads();

  // ---------- finisher ----------
  const int r2 = tid>>2, cs = (tid&3)*16;
  const int rsw2 = (r2&7)<<4;
  if (MODE==0){
    const int edge = s_edge[r2];
    float vals[16];
    #pragma unroll
    for (int c=0;c<16;c++) vals[c]=*(const float*)(h1 + r2*256 + (((cs+c)*4)^rsw2));
    rmw16(e_b + (size_t)edge*64 + cs, vals);       // e += e_new
    // run-length-reduced segment_sum(e_new, dcol) — slots sorted by dcol
    const int col64 = tid&63, rg = tid>>6;
    float ssum = 0.f; int cur = -1;
    #pragma unroll
    for (int rr=0;rr<16;rr++){
      int row = rg*16+rr;
      int gid = s_dcol[row];
      float v = *(const float*)(h1 + row*256 + ((col64*4) ^ ((row&7)<<4)));
      if (gid != cur){ if (cur>=0) unsafeAtomicAdd(eagg + (size_t)cur*64 + col64, ssum); ssum=0.f; cur=gid; }
      ssum += v;
    }
    if (cur>=0) unsafeAtomicAdd(eagg + (size_t)cur*64 + col64, ssum);
  } else if (MODE==1){
    const int node = rowbase + r2;
    if (node < NN){
      float vals[16];
      #pragma unroll
      for (int c=0;c<16;c++) vals[c]=*(const float*)(h1 + r2*256 + (((cs+c)*4)^rsw2));
      rmw16(xh_b + (size_t)node*64 + cs, vals);             // xh += x_new
    }
    // per-graph reduction of x_new (batch sorted -> few runs per block)
    const int col = tid&63, rg = tid>>6;
    float s = 0.f; int cur = -1;
    for (int rr=0;rr<16;rr++){
      int row = rg*16+rr; int nd = rowbase+row;
      int gid = (nd<NN) ? batch[nd] : -1;
      float v = *(const float*)(h1 + row*256 + ((col*4) ^ ((row&7)<<4)));
      if (gid != cur){ if (cur>=0) unsafeAtomicAdd(xagg + cur*64 + col, s); s=0.f; cur=gid; }
      if (gid>=0) s += v;
    }
    if (cur>=0) unsafeAtomicAdd(xagg + cur*64 + col, s);
  } else {
    float vals[16];
    #pragma unroll
    for (int c=0;c<16;c++) vals[c]=*(const float*)(h1 + r2*256 + (((cs+c)*4)^rsw2));
    #pragma unroll
    for (int c=0;c<16;c++){
      int idx = r2*64 + cs + c;
      float nv = g_f[idx] + vals[c];
      g_f[idx] = nv; g_b[idx] = f2b(nv);     // g += g_new (fp32 master + bf16 copy)
    }
  }
}

// ---------------- edge decoder: out[e] = e_row . dec_w + dec_b  (fp32 out)
__global__ __launch_bounds__(256) void k_dec(const u16* __restrict__ e_b, const float* __restrict__ dec_w,
                                             const float* __restrict__ dec_b, float* __restrict__ out){
  __shared__ float wl[64];
  __shared__ float bsh;
  int tid=threadIdx.x;
  if (tid<64) wl[tid]=dec_w[tid];
  if (tid==0) bsh=dec_b[0];
  __syncthreads();
  size_t row = (size_t)blockIdx.x*256 + tid;
  if (row>=EE) return;
  const uint4* s4=(const uint4*)(e_b + row*64);
  float s=bsh;
  #pragma unroll
  for (int j=0;j<8;j++){
    uint4 q=s4[j];
    const u16* h=(const u16*)&q;
    #pragma unroll
    for (int t2=0;t2<8;t2++) s += b2f(h[t2])*wl[j*8+t2];
  }
  out[row]=s;
}

// ---------------- value head: lrelu(g @ vw1 + vb1) @ vw2 + vb2  (fp32 out)
__global__ void k_value(const float* __restrict__ g_f, const float* __restrict__ vw1, const float* __restrict__ vb1,
                        const float* __restrict__ vw2, const float* __restrict__ vb2, float* __restrict__ out){
  __shared__ float w1[4096];
  __shared__ float b1s[64];
  __shared__ float w2[64];
  int tid=threadIdx.x; // 64
  for (int i=tid;i<4096;i+=64) w1[i]=vw1[i];
  if (tid<64){ b1s[tid]=vb1[tid]; w2[tid]=vw2[tid]; }
  __syncthreads();
  float gi[64];
  #pragma unroll
  for (int k=0;k<64;k++) gi[k]=g_f[tid*64+k];
  float val=vb2[0];
  for (int j=0;j<64;j++){
    float s=b1s[j];
    #pragma unroll
    for (int k=0;k<64;k++) s+=gi[k]*w1[k*64+j];
    val += lrelu(s)*w2[j];
  }
  out[tid]=val;
}

extern "C" void kernel_launch(void* const* d_in, const int* in_sizes, int n_in,
                              void* d_out, int out_size, void* d_ws, size_t ws_size,
                              hipStream_t stream){
  const float* x    =(const float*)d_in[0];
  const float* ea   =(const float*)d_in[1];
  const float* uu   =(const float*)d_in[2];
  const float* eew  =(const float*)d_in[3];
  const float* eeb  =(const float*)d_in[4];
  const float* enw  =(const float*)d_in[5];
  const float* enb  =(const float*)d_in[6];
  const float* egw  =(const float*)d_in[7];
  const float* egb  =(const float*)d_in[8];
  const float* ew1  =(const float*)d_in[9];
  const float* eb1  =(const float*)d_in[10];
  const float* ew2  =(const float*)d_in[11];
  const float* eb2  =(const float*)d_in[12];
  const float* ew3  =(const float*)d_in[13];
  const float* eb3  =(const float*)d_in[14];
  const float* nw1  =(const float*)d_in[15];
  const float* nb1  =(const float*)d_in[16];
  const float* nw2  =(const float*)d_in[17];
  const float* nb2  =(const float*)d_in[18];
  const float* nw3  =(const float*)d_in[19];
  const float* nb3  =(const float*)d_in[20];
  const float* gw1  =(const float*)d_in[21];
  const float* gb1  =(const float*)d_in[22];
  const float* gw2  =(const float*)d_in[23];
  const float* gb2  =(const float*)d_in[24];
  const float* gw3  =(const float*)d_in[25];
  const float* gb3  =(const float*)d_in[26];
  const float* dw   =(const float*)d_in[27];
  const float* db   =(const float*)d_in[28];
  const float* vw1  =(const float*)d_in[29];
  const float* vb1  =(const float*)d_in[30];
  const float* vw2  =(const float*)d_in[31];
  const float* vb2  =(const float*)d_in[32];
  const int* eidx =(const int*)d_in[33];
  const int* batch=(const int*)d_in[34];

  char* ws=(char*)d_ws; size_t off=0;
  auto alloc=[&](size_t b)->char*{ char* p=ws+off; off=(off+b+255)&~(size_t)255; return p; };
  u16*   xh_b =(u16*)  alloc((size_t)NN*64*2);
  u16*   e_b  =(u16*)  alloc((size_t)EE*64*2);
  float* eagg =(float*)alloc((size_t)NN*64*4);
  float* xagg =(float*)alloc((size_t)BB*64*4);
  u16*   g_bb =(u16*)  alloc((size_t)BB*64*2);
  float* g_f  =(float*)alloc((size_t)BB*64*4);
  u16* ew1f=(u16*)alloc((size_t)PP*4096*16);
  u16* ew2f=(u16*)alloc((size_t)PP*2048*16);
  u16* ew3f=(u16*)alloc((size_t)PP*1024*16);
  u16* nw1f=(u16*)alloc((size_t)PP*3072*16);
  u16* nw2f=(u16*)alloc((size_t)PP*2048*16);
  u16* nw3f=(u16*)alloc((size_t)PP*1024*16);
  u16* gw1f=(u16*)alloc((size_t)PP*2048*16);
  u16* gw2f=(u16*)alloc((size_t)PP*2048*16);
  u16* gw3f=(u16*)alloc((size_t)PP*1024*16);
  int* hist =(int*)alloc((size_t)NN*4);
  int* offs =(int*)alloc((size_t)NN*4);
  int* perm =(int*)alloc((size_t)EE*4);
  int* dcols=(int*)alloc((size_t)EE*4);
  float* out=(float*)d_out;

  // ---- counting sort of edges by destination ----
  hipMemsetAsync(hist, 0, (size_t)NN*4, stream);
  k_hist<<<(EE+255)/256,256,0,stream>>>(eidx, hist);
  k_scan<<<1,1024,0,stream>>>(hist, offs);
  k_scatter<<<(EE+255)/256,256,0,stream>>>(eidx, offs, perm, dcols);

  auto rp=[&](const float* W, u16* dst, int K, int Nn){
    int total = PP*(K/32)*(Nn/16)*64;
    k_repack<<<(total+255)/256,256,0,stream>>>(W,dst,K,Nn);
  };
  rp(ew1,ew1f,256,128); rp(ew2,ew2f,128,128); rp(ew3,ew3f,128,64);
  rp(nw1,nw1f,192,128); rp(nw2,nw2f,128,128); rp(nw3,nw3f,128,64);
  rp(gw1,gw1f,128,128); rp(gw2,gw2f,128,128); rp(gw3,gw3f,128,64);

  k_embed<<<(EE+255)/256,256,0,stream>>>(ea, eew, eeb, e_b, EE);
  k_embed<<<(NN+255)/256,256,0,stream>>>(x,  enw, enb, xh_b, NN);
  k_embed_g<<<1,64,0,stream>>>(uu, egw, egb, g_bb, g_f);

  for (int p=0;p<PP;p++){
    hipMemsetAsync(eagg, 0, (size_t)NN*64*4, stream);
    hipMemsetAsync(xagg, 0, (size_t)BB*64*4, stream);
    k_mlp<256,0><<<EE/64,256,0,stream>>>(xh_b,e_b,eagg,xagg,g_bb,g_f,eidx,batch,perm,dcols,
        (const uint4*)ew1f + (size_t)p*4096, (const uint4*)ew2f + (size_t)p*2048, (const uint4*)ew3f + (size_t)p*1024,
        eb1+p*128, eb2+p*128, eb3+p*64);
    k_mlp<192,1><<<(NN+63)/64,256,0,stream>>>(xh_b,e_b,eagg,xagg,g_bb,g_f,eidx,batch,perm,dcols,
        (const uint4*)nw1f + (size_t)p*3072, (const uint4*)nw2f + (size_t)p*2048, (const uint4*)nw3f + (size_t)p*1024,
        nb1+p*128, nb2+p*128, nb3+p*64);
    k_mlp<128,2><<<1,256,0,stream>>>(xh_b,e_b,eagg,xagg,g_bb,g_f,eidx,batch,perm,dcols,
        (const uint4*)gw1f + (size_t)p*2048, (const uint4*)gw2f + (size_t)p*2048, (const uint4*)gw3f + (size_t)p*1024,
        gb1+p*128, gb2+p*128, gb3+p*64);
  }
  k_dec<<<(EE+255)/256,256,0,stream>>>(e_b, dw, db, out);
  k_value<<<1,64,0,stream>>>(g_f, vw1, vb1, vw2, vb2, out+EE);
}

// Round 4
// 1411.461 us; speedup vs baseline: 6.7772x; 1.5304x over previous
//
#include <hip/hip_runtime.h>
#include <hip/hip_bf16.h>
#include <stdint.h>

typedef unsigned short u16;
typedef unsigned int u32;
typedef short s16x8 __attribute__((ext_vector_type(8)));
typedef float f32x4 __attribute__((ext_vector_type(4)));

#define NN 50000
#define EE 800000
#define BB 64
#define PP 3

__device__ __forceinline__ float b2f(u16 x){ union{u32 u; float f;} c; c.u=((u32)x)<<16; return c.f; }
__device__ __forceinline__ u16 f2b(float v){ union{float f; u32 u;} c; c.f=v; u32 u=c.u; return (u16)((u + 0x7fffu + ((u>>16)&1u))>>16); }
__device__ __forceinline__ float lrelu(float v){ return v>0.f ? v : 0.01f*v; }
__device__ __forceinline__ f32x4 MFMA(s16x8 a, s16x8 b, f32x4 c){
  return __builtin_amdgcn_mfma_f32_16x16x32_bf16(a,b,c,0,0,0);
}

// async global->LDS, 16B per lane; LDS dest = wave-uniform base + lane*16
__device__ __forceinline__ void gload_lds16(const uint4* g, char* l){
#if defined(__has_builtin) && __has_builtin(__builtin_amdgcn_global_load_lds)
  __builtin_amdgcn_global_load_lds((const __attribute__((address_space(1))) void*)g,
                                   (__attribute__((address_space(3))) void*)l, 16, 0, 0);
#else
  int lane = threadIdx.x & 63;
  *(uint4*)(l + lane*16) = g[lane];
#endif
}

// stage NFR fragments (1KB each) of repacked weights into dst; 4 waves share
template<int NFR>
__device__ __forceinline__ void stage_w(const uint4* __restrict__ w, int fbase, char* dst, int wave, int lane){
  #pragma unroll
  for (int t=0;t<NFR/4;t++){
    int f = wave*(NFR/4) + t;
    gload_lds16(w + (size_t)(fbase+f)*64 + lane, dst + f*1024);
  }
}

// ---------------- counting sort of edges by destination ----------------
__global__ __launch_bounds__(256) void k_hist(const int* __restrict__ eidx, int* __restrict__ hist){
  int e = blockIdx.x*256 + threadIdx.x;
  if (e < EE) atomicAdd(&hist[eidx[EE+e]], 1);
}

__global__ __launch_bounds__(1024) void k_scan(const int* __restrict__ hist, int* __restrict__ offs){
  __shared__ int lsums[1024];
  const int tid = threadIdx.x;
  const int CH = 49; // 1024*49 = 50176 >= NN
  int base = tid*CH;
  int s = 0;
  for (int i=0;i<CH;i++){ int b=base+i; if (b<NN) s += hist[b]; }
  lsums[tid]=s; __syncthreads();
  for (int off=1; off<1024; off<<=1){
    int v = (tid>=off)? lsums[tid-off] : 0;
    __syncthreads();
    lsums[tid] += v;
    __syncthreads();
  }
  int run = (tid>0)? lsums[tid-1] : 0;
  for (int i=0;i<CH;i++){ int b=base+i; if (b<NN){ offs[b]=run; run+=hist[b]; } }
}

__global__ __launch_bounds__(256) void k_scatter(const int* __restrict__ eidx, int* __restrict__ offs,
                                                 int* __restrict__ perm, int* __restrict__ dcols){
  int e = blockIdx.x*256 + threadIdx.x;
  if (e >= EE) return;
  int col = eidx[EE+e];
  int pos = atomicAdd(&offs[col], 1);
  perm[pos] = e;
  dcols[pos] = col;
}

// ---------------- weight repack: fp32 [P][K][N] row-major -> bf16 per-lane MFMA B fragments
__global__ __launch_bounds__(256) void k_repack(const float* __restrict__ W, u16* __restrict__ out, int K, int Nn){
  int chunks_pp = (K/32)*(Nn/16)*64;
  int t = blockIdx.x*256 + threadIdx.x;
  if (t >= PP*chunks_pp) return;
  int p = t/chunks_pp, rem = t%chunks_pp;
  int NB = Nn/16;
  int kb = rem/(NB*64); int r2 = rem%(NB*64);
  int nb = r2/64; int l = r2&63;
  const float* Wp = W + (size_t)p*K*Nn;
  int k0 = kb*32 + ((l>>4)<<3), n = nb*16 + (l&15);
  u16 tmp[8];
  #pragma unroll
  for (int j=0;j<8;j++) tmp[j] = f2b(Wp[(size_t)(k0+j)*Nn + n]);
  *(uint4*)(out + (size_t)t*8) = *(uint4*)tmp;
}

// ---------------- embeddings: out[row] = lrelu(in[row,0:16] @ W[16,64] + b)  (fp32 in -> bf16 out)
__global__ __launch_bounds__(256) void k_embed(const float* __restrict__ in, const float* __restrict__ W,
                                               const float* __restrict__ b, u16* __restrict__ out, int nrows){
  __shared__ float wl[1024];
  __shared__ float bl[64];
  int tid = threadIdx.x;
  for (int i=tid;i<1024;i+=256) wl[i]=W[i];
  if (tid<64) bl[tid]=b[tid];
  __syncthreads();
  int row = blockIdx.x*256 + tid;
  if (row >= nrows) return;
  float inb[16];
  const float4* src4=(const float4*)(in + (size_t)row*16);
  #pragma unroll
  for (int q=0;q<4;q++){ float4 v=src4[q]; inb[q*4]=v.x; inb[q*4+1]=v.y; inb[q*4+2]=v.z; inb[q*4+3]=v.w; }
  float acc[64];
  #pragma unroll
  for (int j=0;j<64;j++) acc[j]=bl[j];
  #pragma unroll
  for (int k=0;k<16;k++){
    float a = inb[k];
    const float4* wr4 = (const float4*)(wl + k*64);
    #pragma unroll
    for (int j4=0;j4<16;j4++){
      float4 w4 = wr4[j4];
      acc[j4*4+0] += a*w4.x; acc[j4*4+1] += a*w4.y;
      acc[j4*4+2] += a*w4.z; acc[j4*4+3] += a*w4.w;
    }
  }
  u16 ob[64];
  #pragma unroll
  for (int j=0;j<64;j++) ob[j]=f2b(lrelu(acc[j]));
  uint4* dst=(uint4*)(out + (size_t)row*64);
  #pragma unroll
  for (int j=0;j<8;j++) dst[j]=((uint4*)ob)[j];
}

__global__ void k_embed_g(const float* __restrict__ in, const float* __restrict__ W, const float* __restrict__ b,
                          u16* __restrict__ g_b, float* __restrict__ g_f){
  __shared__ float wl[1024];
  __shared__ float bl[64];
  int tid = threadIdx.x; // 64 threads
  for (int i=tid;i<1024;i+=64) wl[i]=W[i];
  if (tid<64) bl[tid]=b[tid];
  __syncthreads();
  int row = tid;
  float inb[16];
  const float4* src4=(const float4*)(in + (size_t)row*16);
  #pragma unroll
  for (int q=0;q<4;q++){ float4 v=src4[q]; inb[q*4]=v.x; inb[q*4+1]=v.y; inb[q*4+2]=v.z; inb[q*4+3]=v.w; }
  float acc[64];
  #pragma unroll
  for (int j=0;j<64;j++) acc[j]=bl[j];
  #pragma unroll
  for (int k=0;k<16;k++){
    float a = inb[k];
    const float* wr = wl + k*64;
    #pragma unroll
    for (int j=0;j<64;j++) acc[j] += a*wr[j];
  }
  #pragma unroll
  for (int j=0;j<64;j++){
    float v = lrelu(acc[j]);
    g_f[row*64+j] = v;
    g_b[row*64+j] = f2b(v);
  }
}

// RMW helper: 16 contiguous bf16 += vals
__device__ __forceinline__ void rmw16(u16* p, const float* vals){
  uint4 q0=((uint4*)p)[0], q1=((uint4*)p)[1];
  const u16* h0=(const u16*)&q0; const u16* hq=(const u16*)&q1;
  u16 o[16];
  #pragma unroll
  for (int c=0;c<8;c++) o[c]=f2b(b2f(h0[c])+vals[c]);
  #pragma unroll
  for (int c=0;c<8;c++) o[8+c]=f2b(b2f(hq[c])+vals[8+c]);
  ((uint4*)p)[0]=*(uint4*)o; ((uint4*)p)[1]=*(uint4*)(o+8);
}

// ---------------- fused 3-layer MLP per 64 rows.
// MODE 0: edge model (dest-sorted slots), MODE 1: node model, MODE 2: global model.
// LAST: fuse edge decoder (only used with MODE 0, pass 3).
template<int K0, int MODE, bool LAST>
__global__ __launch_bounds__(256,3) void k_mlp(
    u16* __restrict__ xh_b, u16* __restrict__ e_b,
    float* __restrict__ eagg, float* __restrict__ xagg,
    u16* __restrict__ g_b, float* __restrict__ g_f,
    const int* __restrict__ eidx, const int* __restrict__ batch,
    const int* __restrict__ perm, const int* __restrict__ dcols,
    const uint4* __restrict__ w1f, const uint4* __restrict__ w2f, const uint4* __restrict__ w3f,
    const float* __restrict__ b1, const float* __restrict__ b2, const float* __restrict__ b3,
    const float* __restrict__ dw, const float* __restrict__ db, float* __restrict__ outp)
{
  constexpr int KB  = K0/32;
  constexpr int RS  = K0*2;   // a0 row stride bytes
  // a0: gather buffer; hidden-layer buffers h1/h2/h3 alias its first 16KB
  // (all LDS traffic is wave-banded; cross-wave reuse ordered by the per-kb barriers)
  __shared__ __align__(16) char a0[64*RS];
  __shared__ __align__(16) char wst[2][8192];
  __shared__ int s_edge[64];
  __shared__ int s_dcol[64];
  char* h = a0;

  const int tid  = threadIdx.x;
  const int wave = tid>>6, lane = tid&63;
  const int rowbase = blockIdx.x*64;

  // ---------- prefetch W1 chunk 0 ----------
  stage_w<8>(w1f, 0, wst[0], wave, lane);

  // ---------- gather input rows into swizzled a0 (wave-banded rows) ----------
  {
    const int r = tid>>2, s = tid&3;
    char* drow = a0 + r*RS;
    const int sw = (r&7)<<4;
    if (MODE==0){
      const int slot = rowbase + r;
      const int edge = perm[slot];
      if (s==0){ s_edge[r]=edge; s_dcol[r]=dcols[slot]; }
      const int er = eidx[edge], ec = eidx[EE+edge];
      const u16* src = (s==0)? xh_b + (size_t)er*64
                     : (s==1)? xh_b + (size_t)ec*64
                     : (s==2)? e_b  + (size_t)edge*64
                     :         g_b  + (size_t)batch[er]*64;
      const uint4* s4=(const uint4*)src;
      #pragma unroll
      for (int j=0;j<8;j++)
        *(uint4*)(drow + ((s*128 + j*16) ^ sw)) = s4[j];
    } else if (MODE==1){
      const int node = rowbase + r;
      const bool ok = node < NN;
      if (s==0){
        const uint4* s4=(const uint4*)(xh_b + (size_t)node*64);
        #pragma unroll
        for (int j=0;j<8;j++){ uint4 v={0,0,0,0}; if (ok) v=s4[j];
          *(uint4*)(drow + ((j*16) ^ sw)) = v; }
      } else if (s==1){
        const float4* s4=(const float4*)(eagg + (size_t)node*64);
        #pragma unroll
        for (int j=0;j<8;j++){
          u16 tmp[8]={0,0,0,0,0,0,0,0};
          if (ok){ float4 lo=s4[2*j], hi=s4[2*j+1];
            tmp[0]=f2b(lo.x);tmp[1]=f2b(lo.y);tmp[2]=f2b(lo.z);tmp[3]=f2b(lo.w);
            tmp[4]=f2b(hi.x);tmp[5]=f2b(hi.y);tmp[6]=f2b(hi.z);tmp[7]=f2b(hi.w); }
          *(uint4*)(drow + ((128 + j*16) ^ sw)) = *(uint4*)tmp;
        }
      } else if (s==2){
        int bidx = ok ? batch[node] : 0;
        const uint4* s4=(const uint4*)(g_b + (size_t)bidx*64);
        #pragma unroll
        for (int j=0;j<8;j++){ uint4 v={0,0,0,0}; if (ok) v=s4[j];
          *(uint4*)(drow + ((256 + j*16) ^ sw)) = v; }
      }
    } else { // GLOB: 64 graphs, all valid
      if (s==0){
        const uint4* s4=(const uint4*)(g_b + (size_t)r*64);
        #pragma unroll
        for (int j=0;j<8;j++) *(uint4*)(drow + ((j*16) ^ sw)) = s4[j];
      } else if (s==1){
        const float4* s4=(const float4*)(xagg + (size_t)r*64);
        #pragma unroll
        for (int j=0;j<8;j++){
          u16 tmp[8];
          float4 lo=s4[2*j], hi=s4[2*j+1];
          tmp[0]=f2b(lo.x);tmp[1]=f2b(lo.y);tmp[2]=f2b(lo.z);tmp[3]=f2b(lo.w);
          tmp[4]=f2b(hi.x);tmp[5]=f2b(hi.y);tmp[6]=f2b(hi.z);tmp[7]=f2b(hi.w);
          *(uint4*)(drow + ((128 + j*16) ^ sw)) = *(uint4*)tmp;
        }
      }
    }
  }
  __syncthreads();   // gather + W1 chunk 0 ready

  const int arow = wave*16 + (lane&15);
  const int asw  = (arow&7)<<4;
  const int aoff = (lane>>4)*16;

  int buf = 0;
  f32x4 acc[8];
  #pragma unroll
  for (int nb=0;nb<8;nb++) acc[nb]=f32x4{0.f,0.f,0.f,0.f};

  // ---------- layer 1 (K0 -> 128), per-kb double-buffered weight stream ----------
  #pragma unroll
  for (int kb=0; kb<KB; ++kb){
    if (kb+1<KB) stage_w<8>(w1f,(kb+1)*8, wst[buf^1], wave, lane);
    else         stage_w<8>(w2f, 0,       wst[buf^1], wave, lane);   // prefetch W2 kb0
    s16x8 af = *(const s16x8*)(a0 + arow*RS + ((kb*64 + aoff) ^ asw));
    #pragma unroll
    for (int nb=0;nb<8;nb++)
      acc[nb] = MFMA(af, ((const s16x8*)wst[buf])[nb*64+lane], acc[nb]);
    __syncthreads();
    buf ^= 1;
  }
  // epilogue 1 -> h (bf16, swizzled 256B rows, own wave band)
  #pragma unroll
  for (int nb=0;nb<8;nb++){
    int col = nb*16 + (lane&15);
    float bias = b1[col];
    #pragma unroll
    for (int r=0;r<4;r++){
      int orow = wave*16 + ((lane>>4)<<2) + r;
      *(u16*)(h + orow*256 + ((col*2) ^ ((orow&7)<<4))) = f2b(lrelu(acc[nb][r] + bias));
    }
  }

  // ---------- layer 2 (128 -> 128) ----------
  f32x4 acc2[8];
  #pragma unroll
  for (int nb=0;nb<8;nb++) acc2[nb]=f32x4{0.f,0.f,0.f,0.f};
  #pragma unroll
  for (int kb=0; kb<4; ++kb){
    if (kb<3) stage_w<8>(w2f,(kb+1)*8, wst[buf^1], wave, lane);
    else      stage_w<4>(w3f, 0,       wst[buf^1], wave, lane);      // prefetch W3 kb0
    s16x8 af = *(const s16x8*)(h + arow*256 + ((kb*64 + aoff) ^ asw));
    #pragma unroll
    for (int nb=0;nb<8;nb++)
      acc2[nb] = MFMA(af, ((const s16x8*)wst[buf])[nb*64+lane], acc2[nb]);
    __syncthreads();
    buf ^= 1;
  }
  // epilogue 2 -> h (overwrite, own band; all layer-2 reads done at last barrier)
  #pragma unroll
  for (int nb=0;nb<8;nb++){
    int col = nb*16 + (lane&15);
    float bias = b2[col];
    #pragma unroll
    for (int r=0;r<4;r++){
      int orow = wave*16 + ((lane>>4)<<2) + r;
      *(u16*)(h + orow*256 + ((col*2) ^ ((orow&7)<<4))) = f2b(lrelu(acc2[nb][r] + bias));
    }
  }

  // ---------- layer 3 (128 -> 64, no activation) ----------
  f32x4 acc3[4];
  #pragma unroll
  for (int nb=0;nb<4;nb++) acc3[nb]=f32x4{0.f,0.f,0.f,0.f};
  #pragma unroll
  for (int kb=0; kb<4; ++kb){
    if (kb<3) stage_w<4>(w3f,(kb+1)*4, wst[buf^1], wave, lane);
    s16x8 af = *(const s16x8*)(h + arow*256 + ((kb*64 + aoff) ^ asw));
    #pragma unroll
    for (int nb=0;nb<4;nb++)
      acc3[nb] = MFMA(af, ((const s16x8*)wst[buf])[nb*64+lane], acc3[nb]);
    if (kb<3) __syncthreads();
    buf ^= 1;
  }
  // epilogue 3: fp32 output into h (own band)
  #pragma unroll
  for (int nb=0;nb<4;nb++){
    int col = nb*16 + (lane&15);
    float bias = b3[col];
    #pragma unroll
    for (int r=0;r<4;r++){
      int orow = wave*16 + ((lane>>4)<<2) + r;
      *(float*)(h + orow*256 + ((col*4) ^ ((orow&7)<<4))) = acc3[nb][r] + bias;
    }
  }

  // ---------- finisher (all h reads wave-banded; no barrier needed) ----------
  const int r2 = tid>>2, cs = (tid&3)*16;
  const int rsw2 = (r2&7)<<4;
  if (MODE==0){
    const int edge = s_edge[r2];
    float vals[16];
    #pragma unroll
    for (int c=0;c<16;c++) vals[c]=*(const float*)(h + r2*256 + (((cs+c)*4)^rsw2));
    if (LAST){
      // e += e_new, then fused decode: dot(new bf16 e_row, dec_w) + dec_b
      u16* p = e_b + (size_t)edge*64 + cs;
      uint4 q0=((uint4*)p)[0], q1=((uint4*)p)[1];
      const u16* h0=(const u16*)&q0; const u16* hq=(const u16*)&q1;
      float dwl[16];
      const float4* dw4 = (const float4*)(dw + cs);
      #pragma unroll
      for (int q=0;q<4;q++){ float4 v=dw4[q]; dwl[q*4]=v.x; dwl[q*4+1]=v.y; dwl[q*4+2]=v.z; dwl[q*4+3]=v.w; }
      u16 o[16]; float part=0.f;
      #pragma unroll
      for (int c=0;c<8;c++){ u16 nb16=f2b(b2f(h0[c])+vals[c]); o[c]=nb16; part += b2f(nb16)*dwl[c]; }
      #pragma unroll
      for (int c=0;c<8;c++){ u16 nb16=f2b(b2f(hq[c])+vals[8+c]); o[8+c]=nb16; part += b2f(nb16)*dwl[8+c]; }
      ((uint4*)p)[0]=*(uint4*)o; ((uint4*)p)[1]=*(uint4*)(o+8);
      part += __shfl_xor(part,1);
      part += __shfl_xor(part,2);
      if ((tid&3)==0) outp[edge] = part + db[0];
    } else {
      rmw16(e_b + (size_t)edge*64 + cs, vals);       // e += e_new
    }
    // run-length-reduced segment_sum(e_new, dcol) — slots sorted by dcol
    const int col64 = tid&63, rg = tid>>6;
    float ssum = 0.f; int cur = -1;
    #pragma unroll
    for (int rr=0;rr<16;rr++){
      int row = rg*16+rr;
      int gid = s_dcol[row];
      float v = *(const float*)(h + row*256 + ((col64*4) ^ ((row&7)<<4)));
      if (gid != cur){ if (cur>=0) unsafeAtomicAdd(eagg + (size_t)cur*64 + col64, ssum); ssum=0.f; cur=gid; }
      ssum += v;
    }
    if (cur>=0) unsafeAtomicAdd(eagg + (size_t)cur*64 + col64, ssum);
  } else if (MODE==1){
    const int node = rowbase + r2;
    if (node < NN){
      float vals[16];
      #pragma unroll
      for (int c=0;c<16;c++) vals[c]=*(const float*)(h + r2*256 + (((cs+c)*4)^rsw2));
      rmw16(xh_b + (size_t)node*64 + cs, vals);             // xh += x_new
    }
    // per-graph reduction of x_new (batch sorted -> few runs per block)
    const int col = tid&63, rg = tid>>6;
    float s = 0.f; int cur = -1;
    for (int rr=0;rr<16;rr++){
      int row = rg*16+rr; int nd = rowbase+row;
      int gid = (nd<NN) ? batch[nd] : -1;
      float v = *(const float*)(h + row*256 + ((col*4) ^ ((row&7)<<4)));
      if (gid != cur){ if (cur>=0) unsafeAtomicAdd(xagg + cur*64 + col, s); s=0.f; cur=gid; }
      if (gid>=0) s += v;
    }
    if (cur>=0) unsafeAtomicAdd(xagg + cur*64 + col, s);
  } else {
    float vals[16];
    #pragma unroll
    for (int c=0;c<16;c++) vals[c]=*(const float*)(h + r2*256 + (((cs+c)*4)^rsw2));
    #pragma unroll
    for (int c=0;c<16;c++){
      int idx = r2*64 + cs + c;
      float nv = g_f[idx] + vals[c];
      g_f[idx] = nv; g_b[idx] = f2b(nv);     // g += g_new (fp32 master + bf16 copy)
    }
  }
}

// ---------------- value head: lrelu(g @ vw1 + vb1) @ vw2 + vb2  (fp32 out)
__global__ void k_value(const float* __restrict__ g_f, const float* __restrict__ vw1, const float* __restrict__ vb1,
                        const float* __restrict__ vw2, const float* __restrict__ vb2, float* __restrict__ out){
  __shared__ float w1[4096];
  __shared__ float b1s[64];
  __shared__ float w2[64];
  int tid=threadIdx.x; // 64
  for (int i=tid;i<4096;i+=64) w1[i]=vw1[i];
  if (tid<64){ b1s[tid]=vb1[tid]; w2[tid]=vw2[tid]; }
  __syncthreads();
  float gi[64];
  #pragma unroll
  for (int k=0;k<64;k++) gi[k]=g_f[tid*64+k];
  float val=vb2[0];
  for (int j=0;j<64;j++){
    float s=b1s[j];
    #pragma unroll
    for (int k=0;k<64;k++) s+=gi[k]*w1[k*64+j];
    val += lrelu(s)*w2[j];
  }
  out[tid]=val;
}

extern "C" void kernel_launch(void* const* d_in, const int* in_sizes, int n_in,
                              void* d_out, int out_size, void* d_ws, size_t ws_size,
                              hipStream_t stream){
  const float* x    =(const float*)d_in[0];
  const float* ea   =(const float*)d_in[1];
  const float* uu   =(const float*)d_in[2];
  const float* eew  =(const float*)d_in[3];
  const float* eeb  =(const float*)d_in[4];
  const float* enw  =(const float*)d_in[5];
  const float* enb  =(const float*)d_in[6];
  const float* egw  =(const float*)d_in[7];
  const float* egb  =(const float*)d_in[8];
  const float* ew1  =(const float*)d_in[9];
  const float* eb1  =(const float*)d_in[10];
  const float* ew2  =(const float*)d_in[11];
  const float* eb2  =(const float*)d_in[12];
  const float* ew3  =(const float*)d_in[13];
  const float* eb3  =(const float*)d_in[14];
  const float* nw1  =(const float*)d_in[15];
  const float* nb1  =(const float*)d_in[16];
  const float* nw2  =(const float*)d_in[17];
  const float* nb2  =(const float*)d_in[18];
  const float* nw3  =(const float*)d_in[19];
  const float* nb3  =(const float*)d_in[20];
  const float* gw1  =(const float*)d_in[21];
  const float* gb1  =(const float*)d_in[22];
  const float* gw2  =(const float*)d_in[23];
  const float* gb2  =(const float*)d_in[24];
  const float* gw3  =(const float*)d_in[25];
  const float* gb3  =(const float*)d_in[26];
  const float* dw   =(const float*)d_in[27];
  const float* db   =(const float*)d_in[28];
  const float* vw1  =(const float*)d_in[29];
  const float* vb1  =(const float*)d_in[30];
  const float* vw2  =(const float*)d_in[31];
  const float* vb2  =(const float*)d_in[32];
  const int* eidx =(const int*)d_in[33];
  const int* batch=(const int*)d_in[34];

  char* ws=(char*)d_ws; size_t off=0;
  auto alloc=[&](size_t b)->char*{ char* p=ws+off; off=(off+b+255)&~(size_t)255; return p; };
  u16*   xh_b =(u16*)  alloc((size_t)NN*64*2);
  u16*   e_b  =(u16*)  alloc((size_t)EE*64*2);
  float* eagg =(float*)alloc((size_t)NN*64*4);
  float* xagg =(float*)alloc((size_t)BB*64*4);
  u16*   g_bb =(u16*)  alloc((size_t)BB*64*2);
  float* g_f  =(float*)alloc((size_t)BB*64*4);
  u16* ew1f=(u16*)alloc((size_t)PP*4096*16);
  u16* ew2f=(u16*)alloc((size_t)PP*2048*16);
  u16* ew3f=(u16*)alloc((size_t)PP*1024*16);
  u16* nw1f=(u16*)alloc((size_t)PP*3072*16);
  u16* nw2f=(u16*)alloc((size_t)PP*2048*16);
  u16* nw3f=(u16*)alloc((size_t)PP*1024*16);
  u16* gw1f=(u16*)alloc((size_t)PP*2048*16);
  u16* gw2f=(u16*)alloc((size_t)PP*2048*16);
  u16* gw3f=(u16*)alloc((size_t)PP*1024*16);
  int* hist =(int*)alloc((size_t)NN*4);
  int* offs =(int*)alloc((size_t)NN*4);
  int* perm =(int*)alloc((size_t)EE*4);
  int* dcols=(int*)alloc((size_t)EE*4);
  float* out=(float*)d_out;

  // ---- counting sort of edges by destination ----
  hipMemsetAsync(hist, 0, (size_t)NN*4, stream);
  k_hist<<<(EE+255)/256,256,0,stream>>>(eidx, hist);
  k_scan<<<1,1024,0,stream>>>(hist, offs);
  k_scatter<<<(EE+255)/256,256,0,stream>>>(eidx, offs, perm, dcols);

  auto rp=[&](const float* W, u16* dst, int K, int Nn){
    int total = PP*(K/32)*(Nn/16)*64;
    k_repack<<<(total+255)/256,256,0,stream>>>(W,dst,K,Nn);
  };
  rp(ew1,ew1f,256,128); rp(ew2,ew2f,128,128); rp(ew3,ew3f,128,64);
  rp(nw1,nw1f,192,128); rp(nw2,nw2f,128,128); rp(nw3,nw3f,128,64);
  rp(gw1,gw1f,128,128); rp(gw2,gw2f,128,128); rp(gw3,gw3f,128,64);

  k_embed<<<(EE+255)/256,256,0,stream>>>(ea, eew, eeb, e_b, EE);
  k_embed<<<(NN+255)/256,256,0,stream>>>(x,  enw, enb, xh_b, NN);
  k_embed_g<<<1,64,0,stream>>>(uu, egw, egb, g_bb, g_f);

  for (int p=0;p<PP;p++){
    hipMemsetAsync(eagg, 0, (size_t)NN*64*4, stream);
    hipMemsetAsync(xagg, 0, (size_t)BB*64*4, stream);
    if (p<PP-1)
      k_mlp<256,0,false><<<EE/64,256,0,stream>>>(xh_b,e_b,eagg,xagg,g_bb,g_f,eidx,batch,perm,dcols,
          (const uint4*)ew1f + (size_t)p*4096, (const uint4*)ew2f + (size_t)p*2048, (const uint4*)ew3f + (size_t)p*1024,
          eb1+p*128, eb2+p*128, eb3+p*64, dw, db, out);
    else
      k_mlp<256,0,true><<<EE/64,256,0,stream>>>(xh_b,e_b,eagg,xagg,g_bb,g_f,eidx,batch,perm,dcols,
          (const uint4*)ew1f + (size_t)p*4096, (const uint4*)ew2f + (size_t)p*2048, (const uint4*)ew3f + (size_t)p*1024,
          eb1+p*128, eb2+p*128, eb3+p*64, dw, db, out);
    k_mlp<192,1,false><<<(NN+63)/64,256,0,stream>>>(xh_b,e_b,eagg,xagg,g_bb,g_f,eidx,batch,perm,dcols,
        (const uint4*)nw1f + (size_t)p*3072, (const uint4*)nw2f + (size_t)p*2048, (const uint4*)nw3f + (size_t)p*1024,
        nb1+p*128, nb2+p*128, nb3+p*64, dw, db, out);
    k_mlp<128,2,false><<<1,256,0,stream>>>(xh_b,e_b,eagg,xagg,g_bb,g_f,eidx,batch,perm,dcols,
        (const uint4*)gw1f + (size_t)p*2048, (const uint4*)gw2f + (size_t)p*2048, (const uint4*)gw3f + (size_t)p*1024,
        gb1+p*128, gb2+p*128, gb3+p*64, dw, db, out);
  }
  k_value<<<1,64,0,stream>>>(g_f, vw1, vb1, vw2, vb2, out+EE);
}

// Round 5
// 1203.660 us; speedup vs baseline: 7.9473x; 1.1726x over previous
//
#include <hip/hip_runtime.h>
#include <hip/hip_bf16.h>
#include <stdint.h>

typedef unsigned short u16;
typedef unsigned int u32;
typedef short s16x8 __attribute__((ext_vector_type(8)));
typedef float f32x4 __attribute__((ext_vector_type(4)));

#define NN 50000
#define EE 800000
#define BB 64
#define PP 3

__device__ __forceinline__ float b2f(u16 x){ union{u32 u; float f;} c; c.u=((u32)x)<<16; return c.f; }
__device__ __forceinline__ u16 f2b(float v){ union{float f; u32 u;} c; c.f=v; u32 u=c.u; return (u16)((u + 0x7fffu + ((u>>16)&1u))>>16); }
__device__ __forceinline__ float lrelu(float v){ return v>0.f ? v : 0.01f*v; }
__device__ __forceinline__ f32x4 MFMA(s16x8 a, s16x8 b, f32x4 c){
  return __builtin_amdgcn_mfma_f32_16x16x32_bf16(a,b,c,0,0,0);
}

// ---------------- counting sort of edges by destination ----------------
__global__ __launch_bounds__(256) void k_hist(const int* __restrict__ eidx, int* __restrict__ hist){
  int e = blockIdx.x*256 + threadIdx.x;
  if (e < EE) atomicAdd(&hist[eidx[EE+e]], 1);
}

__global__ __launch_bounds__(1024) void k_scan(const int* __restrict__ hist, int* __restrict__ offs){
  __shared__ int lsums[1024];
  const int tid = threadIdx.x;
  const int CH = 49; // 1024*49 = 50176 >= NN
  int base = tid*CH;
  int s = 0;
  for (int i=0;i<CH;i++){ int b=base+i; if (b<NN) s += hist[b]; }
  lsums[tid]=s; __syncthreads();
  for (int off=1; off<1024; off<<=1){
    int v = (tid>=off)? lsums[tid-off] : 0;
    __syncthreads();
    lsums[tid] += v;
    __syncthreads();
  }
  int run = (tid>0)? lsums[tid-1] : 0;
  for (int i=0;i<CH;i++){ int b=base+i; if (b<NN){ offs[b]=run; run+=hist[b]; } }
}

__global__ __launch_bounds__(256) void k_scatter(const int* __restrict__ eidx, int* __restrict__ offs,
                                                 int* __restrict__ perm, int* __restrict__ dcols,
                                                 int* __restrict__ inv){
  int e = blockIdx.x*256 + threadIdx.x;
  if (e >= EE) return;
  int col = eidx[EE+e];
  int pos = atomicAdd(&offs[col], 1);
  perm[pos] = e;
  dcols[pos] = col;
  inv[e] = pos;
}

// ---------------- weight repack: fp32 [P][K][N] row-major -> bf16 per-lane MFMA fragments
// frag element (p, kb, nb, lane, j) = W[p][kb*32 + (lane>>4)*8 + j][nb*16 + (lane&15)]
__global__ __launch_bounds__(256) void k_repack(const float* __restrict__ W, u16* __restrict__ out, int K, int Nn){
  int chunks_pp = (K/32)*(Nn/16)*64;
  int t = blockIdx.x*256 + threadIdx.x;
  if (t >= PP*chunks_pp) return;
  int p = t/chunks_pp, rem = t%chunks_pp;
  int NB = Nn/16;
  int kb = rem/(NB*64); int r2 = rem%(NB*64);
  int nb = r2/64; int l = r2&63;
  const float* Wp = W + (size_t)p*K*Nn;
  int k0 = kb*32 + ((l>>4)<<3), n = nb*16 + (l&15);
  u16 tmp[8];
  #pragma unroll
  for (int j=0;j<8;j++) tmp[j] = f2b(Wp[(size_t)(k0+j)*Nn + n]);
  *(uint4*)(out + (size_t)t*8) = *(uint4*)tmp;
}

// ---------------- embeddings: out[row] = lrelu(in[row,0:16] @ W[16,64] + b)  (fp32 in -> bf16 out)
// SCATTER: write to out[inv[row]] (edge features stored dest-sorted)
template<bool SCATTER>
__global__ __launch_bounds__(256) void k_embed(const float* __restrict__ in, const float* __restrict__ W,
                                               const float* __restrict__ b, u16* __restrict__ out, int nrows,
                                               const int* __restrict__ inv){
  __shared__ float wl[1024];
  __shared__ float bl[64];
  int tid = threadIdx.x;
  for (int i=tid;i<1024;i+=256) wl[i]=W[i];
  if (tid<64) bl[tid]=b[tid];
  __syncthreads();
  int row = blockIdx.x*256 + tid;
  if (row >= nrows) return;
  float inb[16];
  const float4* src4=(const float4*)(in + (size_t)row*16);
  #pragma unroll
  for (int q=0;q<4;q++){ float4 v=src4[q]; inb[q*4]=v.x; inb[q*4+1]=v.y; inb[q*4+2]=v.z; inb[q*4+3]=v.w; }
  float acc[64];
  #pragma unroll
  for (int j=0;j<64;j++) acc[j]=bl[j];
  #pragma unroll
  for (int k=0;k<16;k++){
    float a = inb[k];
    const float4* wr4 = (const float4*)(wl + k*64);
    #pragma unroll
    for (int j4=0;j4<16;j4++){
      float4 w4 = wr4[j4];
      acc[j4*4+0] += a*w4.x; acc[j4*4+1] += a*w4.y;
      acc[j4*4+2] += a*w4.z; acc[j4*4+3] += a*w4.w;
    }
  }
  u16 ob[64];
  #pragma unroll
  for (int j=0;j<64;j++) ob[j]=f2b(lrelu(acc[j]));
  int drow = SCATTER ? inv[row] : row;
  uint4* dst=(uint4*)(out + (size_t)drow*64);
  #pragma unroll
  for (int j=0;j<8;j++) dst[j]=((uint4*)ob)[j];
}

__global__ void k_embed_g(const float* __restrict__ in, const float* __restrict__ W, const float* __restrict__ b,
                          u16* __restrict__ g_b, float* __restrict__ g_f){
  __shared__ float wl[1024];
  __shared__ float bl[64];
  int tid = threadIdx.x; // 64 threads
  for (int i=tid;i<1024;i+=64) wl[i]=W[i];
  if (tid<64) bl[tid]=b[tid];
  __syncthreads();
  int row = tid;
  float inb[16];
  const float4* src4=(const float4*)(in + (size_t)row*16);
  #pragma unroll
  for (int q=0;q<4;q++){ float4 v=src4[q]; inb[q*4]=v.x; inb[q*4+1]=v.y; inb[q*4+2]=v.z; inb[q*4+3]=v.w; }
  float acc[64];
  #pragma unroll
  for (int j=0;j<64;j++) acc[j]=bl[j];
  #pragma unroll
  for (int k=0;k<16;k++){
    float a = inb[k];
    const float* wr = wl + k*64;
    #pragma unroll
    for (int j=0;j<64;j++) acc[j] += a*wr[j];
  }
  #pragma unroll
  for (int j=0;j<64;j++){
    float v = lrelu(acc[j]);
    g_f[row*64+j] = v;
    g_b[row*64+j] = f2b(v);
  }
}

// RMW helper: 16 contiguous bf16 += vals
__device__ __forceinline__ void rmw16(u16* p, const float* vals){
  uint4 q0=((uint4*)p)[0], q1=((uint4*)p)[1];
  const u16* h0=(const u16*)&q0; const u16* hq=(const u16*)&q1;
  u16 o[16];
  #pragma unroll
  for (int c=0;c<8;c++) o[c]=f2b(b2f(h0[c])+vals[c]);
  #pragma unroll
  for (int c=0;c<8;c++) o[8+c]=f2b(b2f(hq[c])+vals[8+c]);
  ((uint4*)p)[0]=*(uint4*)o; ((uint4*)p)[1]=*(uint4*)(o+8);
}

// ---------------- fused 3-layer MLP per 64 rows, weights in registers, waves N-sliced.
// MODE 0: edge model (dest-sorted storage), MODE 1: node model, MODE 2: global model.
// LAST: fuse edge decoder (MODE 0, pass 3).
// MFMA operands swapped: D = mfma(W_frag, X_frag) -> lane holds 4 consecutive out-cols of one row.
template<int K0, int MODE, bool LAST>
__global__ __launch_bounds__(256,3) void k_mlp(
    u16* __restrict__ xh_b, u16* __restrict__ e_b,   // e_b points at dest-sorted e storage
    float* __restrict__ eagg, float* __restrict__ xagg,
    u16* __restrict__ g_b, float* __restrict__ g_f,
    const int* __restrict__ eidx, const int* __restrict__ batch,
    const int* __restrict__ perm, const int* __restrict__ dcols,
    const uint4* __restrict__ w1f, const uint4* __restrict__ w2f, const uint4* __restrict__ w3f,
    const float* __restrict__ b1, const float* __restrict__ b2, const float* __restrict__ b3,
    const float* __restrict__ dw, const float* __restrict__ db, float* __restrict__ outp)
{
  constexpr int KB  = K0/32;
  constexpr int RS  = K0*2;   // a0 row stride bytes
  __shared__ __align__(16) char a0[64*RS];     // gather buffer; h2 reuses first 16KB
  __shared__ __align__(16) char hbuf[16384];   // h1 / h3 (256B rows)
  __shared__ int s_edge[64];
  __shared__ int s_dcol[64];

  const int tid  = threadIdx.x;
  const int wave = tid>>6, lane = tid&63;
  const int rowbase = blockIdx.x*64;
  const int lrow = lane&15;                 // row-within-16 for fragment reads
  const int lsw  = (lane&7)<<4;             // swizzle (row&7)<<4, rb-independent
  const int aoff = (lane>>4)*16;            // k-chunk byte offset within 64B
  const int qc   = (lane>>4)*4;             // out-col quad base

  // ---------- load W1 fragments into registers (N-sliced: this wave's 2 nb) ----------
  s16x8 wA[KB][2];
  #pragma unroll
  for (int kb=0;kb<KB;kb++){
    #pragma unroll
    for (int j=0;j<2;j++)
      wA[kb][j] = *(const s16x8*)(w1f + (size_t)(kb*8 + wave*2 + j)*64 + lane);
  }

  // ---------- gather input rows into swizzled a0 ----------
  {
    const int r = tid>>2, s = tid&3;
    char* drow = a0 + r*RS;
    const int sw = (r&7)<<4;
    if (MODE==0){
      const int slot = rowbase + r;
      const int edge = perm[slot];
      if (s==0){ s_edge[r]=edge; s_dcol[r]=dcols[slot]; }
      const int er = eidx[edge], ec = eidx[EE+edge];
      const u16* src = (s==0)? xh_b + (size_t)er*64
                     : (s==1)? xh_b + (size_t)ec*64
                     : (s==2)? e_b  + (size_t)slot*64          // dest-sorted: contiguous
                     :         g_b  + (size_t)batch[er]*64;
      const uint4* s4=(const uint4*)src;
      #pragma unroll
      for (int j=0;j<8;j++)
        *(uint4*)(drow + ((s*128 + j*16) ^ sw)) = s4[j];
    } else if (MODE==1){
      const int node = rowbase + r;
      const bool ok = node < NN;
      if (s==0){
        const uint4* s4=(const uint4*)(xh_b + (size_t)node*64);
        #pragma unroll
        for (int j=0;j<8;j++){ uint4 v={0,0,0,0}; if (ok) v=s4[j];
          *(uint4*)(drow + ((j*16) ^ sw)) = v; }
      } else if (s==1){
        const float4* s4=(const float4*)(eagg + (size_t)node*64);
        #pragma unroll
        for (int j=0;j<8;j++){
          u16 tmp[8]={0,0,0,0,0,0,0,0};
          if (ok){ float4 lo=s4[2*j], hi=s4[2*j+1];
            tmp[0]=f2b(lo.x);tmp[1]=f2b(lo.y);tmp[2]=f2b(lo.z);tmp[3]=f2b(lo.w);
            tmp[4]=f2b(hi.x);tmp[5]=f2b(hi.y);tmp[6]=f2b(hi.z);tmp[7]=f2b(hi.w); }
          *(uint4*)(drow + ((128 + j*16) ^ sw)) = *(uint4*)tmp;
        }
      } else if (s==2){
        int bidx = ok ? batch[node] : 0;
        const uint4* s4=(const uint4*)(g_b + (size_t)bidx*64);
        #pragma unroll
        for (int j=0;j<8;j++){ uint4 v={0,0,0,0}; if (ok) v=s4[j];
          *(uint4*)(drow + ((256 + j*16) ^ sw)) = v; }
      }
    } else { // GLOB: 64 graphs, all valid
      if (s==0){
        const uint4* s4=(const uint4*)(g_b + (size_t)r*64);
        #pragma unroll
        for (int j=0;j<8;j++) *(uint4*)(drow + ((j*16) ^ sw)) = s4[j];
      } else if (s==1){
        const float4* s4=(const float4*)(xagg + (size_t)r*64);
        #pragma unroll
        for (int j=0;j<8;j++){
          u16 tmp[8];
          float4 lo=s4[2*j], hi=s4[2*j+1];
          tmp[0]=f2b(lo.x);tmp[1]=f2b(lo.y);tmp[2]=f2b(lo.z);tmp[3]=f2b(lo.w);
          tmp[4]=f2b(hi.x);tmp[5]=f2b(hi.y);tmp[6]=f2b(hi.z);tmp[7]=f2b(hi.w);
          *(uint4*)(drow + ((128 + j*16) ^ sw)) = *(uint4*)tmp;
        }
      }
    }
  }
  __syncthreads();   // [1] gather visible

  // ---------- layer 1 (K0 -> 128): acc[rb][j] = W-slice x all 64 rows ----------
  f32x4 acc[4][2];
  #pragma unroll
  for (int rb=0;rb<4;rb++){ acc[rb][0]=f32x4{0,0,0,0}; acc[rb][1]=f32x4{0,0,0,0}; }
  #pragma unroll
  for (int kb=0;kb<KB;kb++){
    #pragma unroll
    for (int rb=0;rb<4;rb++){
      s16x8 af = *(const s16x8*)(a0 + (rb*16+lrow)*RS + ((kb*64 + aoff) ^ lsw));
      acc[rb][0] = MFMA(wA[kb][0], af, acc[rb][0]);
      acc[rb][1] = MFMA(wA[kb][1], af, acc[rb][1]);
    }
  }

  // load W2 fragments (latency hidden under epilogue + barrier)
  s16x8 wB[4][2];
  #pragma unroll
  for (int kb=0;kb<4;kb++){
    #pragma unroll
    for (int j=0;j<2;j++)
      wB[kb][j] = *(const s16x8*)(w2f + (size_t)(kb*8 + wave*2 + j)*64 + lane);
  }

  // epilogue 1 -> hbuf (bf16, packed b64 stores; row = rb*16+lrow, cols = wave*32+j*16+qc..+3)
  #pragma unroll
  for (int j=0;j<2;j++){
    const float4 bs = *(const float4*)(b1 + wave*32 + j*16 + qc);
    #pragma unroll
    for (int rb=0;rb<4;rb++){
      int row = rb*16 + lrow;
      int c2 = (wave*32 + j*16 + qc)*2;
      u16 t0=f2b(lrelu(acc[rb][j][0]+bs.x)), t1=f2b(lrelu(acc[rb][j][1]+bs.y));
      u16 t2=f2b(lrelu(acc[rb][j][2]+bs.z)), t3=f2b(lrelu(acc[rb][j][3]+bs.w));
      uint2 pk = make_uint2((u32)t0 | ((u32)t1<<16), (u32)t2 | ((u32)t3<<16));
      *(uint2*)(hbuf + row*256 + (c2 ^ ((row&7)<<4))) = pk;
    }
  }
  __syncthreads();   // [2] h1 ready

  // ---------- layer 2 (128 -> 128) ----------
  f32x4 acc2[4][2];
  #pragma unroll
  for (int rb=0;rb<4;rb++){ acc2[rb][0]=f32x4{0,0,0,0}; acc2[rb][1]=f32x4{0,0,0,0}; }
  #pragma unroll
  for (int kb=0;kb<4;kb++){
    #pragma unroll
    for (int rb=0;rb<4;rb++){
      s16x8 af = *(const s16x8*)(hbuf + (rb*16+lrow)*256 + ((kb*64 + aoff) ^ lsw));
      acc2[rb][0] = MFMA(wB[kb][0], af, acc2[rb][0]);
      acc2[rb][1] = MFMA(wB[kb][1], af, acc2[rb][1]);
    }
  }

  // load W3 fragments (N=64: 1 nb per wave)
  s16x8 wC[4];
  #pragma unroll
  for (int kb=0;kb<4;kb++)
    wC[kb] = *(const s16x8*)(w3f + (size_t)(kb*4 + wave)*64 + lane);

  // epilogue 2 -> a0 region (h2, 256B rows; gather data dead since barrier [2])
  #pragma unroll
  for (int j=0;j<2;j++){
    const float4 bs = *(const float4*)(b2 + wave*32 + j*16 + qc);
    #pragma unroll
    for (int rb=0;rb<4;rb++){
      int row = rb*16 + lrow;
      int c2 = (wave*32 + j*16 + qc)*2;
      u16 t0=f2b(lrelu(acc2[rb][j][0]+bs.x)), t1=f2b(lrelu(acc2[rb][j][1]+bs.y));
      u16 t2=f2b(lrelu(acc2[rb][j][2]+bs.z)), t3=f2b(lrelu(acc2[rb][j][3]+bs.w));
      uint2 pk = make_uint2((u32)t0 | ((u32)t1<<16), (u32)t2 | ((u32)t3<<16));
      *(uint2*)(a0 + row*256 + (c2 ^ ((row&7)<<4))) = pk;
    }
  }
  __syncthreads();   // [3] h2 ready

  // ---------- layer 3 (128 -> 64, no activation) ----------
  f32x4 acc3[4];
  #pragma unroll
  for (int rb=0;rb<4;rb++) acc3[rb]=f32x4{0,0,0,0};
  #pragma unroll
  for (int kb=0;kb<4;kb++){
    #pragma unroll
    for (int rb=0;rb<4;rb++){
      s16x8 af = *(const s16x8*)(a0 + (rb*16+lrow)*256 + ((kb*64 + aoff) ^ lsw));
      acc3[rb] = MFMA(wC[kb], af, acc3[rb]);
    }
  }
  // epilogue 3 -> hbuf as fp32 (b128 stores); cols wave*16+qc..+3
  {
    const float4 b3v = *(const float4*)(b3 + wave*16 + qc);
    #pragma unroll
    for (int rb=0;rb<4;rb++){
      int row = rb*16 + lrow;
      int c4 = (wave*16 + qc)*4;
      float4 o = make_float4(acc3[rb][0]+b3v.x, acc3[rb][1]+b3v.y, acc3[rb][2]+b3v.z, acc3[rb][3]+b3v.w);
      *(float4*)(hbuf + row*256 + (c4 ^ ((row&7)<<4))) = o;
    }
  }
  __syncthreads();   // [4] h3 ready

  // ---------- finisher ----------
  const int r2 = tid>>2, cs = (tid&3)*16;
  const int rsw2 = (r2&7)<<4;
  if (MODE==0){
    const int slot = rowbase + r2;
    float vals[16];
    #pragma unroll
    for (int c=0;c<16;c++) vals[c]=*(const float*)(hbuf + r2*256 + (((cs+c)*4)^rsw2));
    if (LAST){
      // e += e_new (dest-sorted storage), fused decode into original edge order
      const int edge = s_edge[r2];
      u16* p = e_b + (size_t)slot*64 + cs;
      uint4 q0=((uint4*)p)[0], q1=((uint4*)p)[1];
      const u16* h0=(const u16*)&q0; const u16* hq=(const u16*)&q1;
      float dwl[16];
      const float4* dw4 = (const float4*)(dw + cs);
      #pragma unroll
      for (int q=0;q<4;q++){ float4 v=dw4[q]; dwl[q*4]=v.x; dwl[q*4+1]=v.y; dwl[q*4+2]=v.z; dwl[q*4+3]=v.w; }
      u16 o[16]; float part=0.f;
      #pragma unroll
      for (int c=0;c<8;c++){ u16 nb16=f2b(b2f(h0[c])+vals[c]); o[c]=nb16; part += b2f(nb16)*dwl[c]; }
      #pragma unroll
      for (int c=0;c<8;c++){ u16 nb16=f2b(b2f(hq[c])+vals[8+c]); o[8+c]=nb16; part += b2f(nb16)*dwl[8+c]; }
      ((uint4*)p)[0]=*(uint4*)o; ((uint4*)p)[1]=*(uint4*)(o+8);
      part += __shfl_xor(part,1);
      part += __shfl_xor(part,2);
      if ((tid&3)==0) outp[edge] = part + db[0];
    } else {
      rmw16(e_b + (size_t)slot*64 + cs, vals);       // e += e_new, coalesced
    }
    // run-length-reduced segment_sum(e_new, dcol) — slots sorted by dcol
    const int col64 = tid&63, rg = tid>>6;
    float ssum = 0.f; int cur = -1;
    #pragma unroll
    for (int rr=0;rr<16;rr++){
      int row = rg*16+rr;
      int gid = s_dcol[row];
      float v = *(const float*)(hbuf + row*256 + ((col64*4) ^ ((row&7)<<4)));
      if (gid != cur){ if (cur>=0) unsafeAtomicAdd(eagg + (size_t)cur*64 + col64, ssum); ssum=0.f; cur=gid; }
      ssum += v;
    }
    if (cur>=0) unsafeAtomicAdd(eagg + (size_t)cur*64 + col64, ssum);
  } else if (MODE==1){
    const int node = rowbase + r2;
    if (node < NN){
      float vals[16];
      #pragma unroll
      for (int c=0;c<16;c++) vals[c]=*(const float*)(hbuf + r2*256 + (((cs+c)*4)^rsw2));
      rmw16(xh_b + (size_t)node*64 + cs, vals);             // xh += x_new
    }
    // per-graph reduction of x_new (batch sorted -> few runs per block)
    const int col = tid&63, rg = tid>>6;
    float s = 0.f; int cur = -1;
    for (int rr=0;rr<16;rr++){
      int row = rg*16+rr; int nd = rowbase+row;
      int gid = (nd<NN) ? batch[nd] : -1;
      float v = *(const float*)(hbuf + row*256 + ((col*4) ^ ((row&7)<<4)));
      if (gid != cur){ if (cur>=0) unsafeAtomicAdd(xagg + cur*64 + col, s); s=0.f; cur=gid; }
      if (gid>=0) s += v;
    }
    if (cur>=0) unsafeAtomicAdd(xagg + cur*64 + col, s);
  } else {
    float vals[16];
    #pragma unroll
    for (int c=0;c<16;c++) vals[c]=*(const float*)(hbuf + r2*256 + (((cs+c)*4)^rsw2));
    #pragma unroll
    for (int c=0;c<16;c++){
      int idx = r2*64 + cs + c;
      float nv = g_f[idx] + vals[c];
      g_f[idx] = nv; g_b[idx] = f2b(nv);     // g += g_new (fp32 master + bf16 copy)
    }
  }
}

// ---------------- value head: lrelu(g @ vw1 + vb1) @ vw2 + vb2  (fp32 out)
__global__ void k_value(const float* __restrict__ g_f, const float* __restrict__ vw1, const float* __restrict__ vb1,
                        const float* __restrict__ vw2, const float* __restrict__ vb2, float* __restrict__ out){
  __shared__ float w1[4096];
  __shared__ float b1s[64];
  __shared__ float w2[64];
  int tid=threadIdx.x; // 64
  for (int i=tid;i<4096;i+=64) w1[i]=vw1[i];
  if (tid<64){ b1s[tid]=vb1[tid]; w2[tid]=vw2[tid]; }
  __syncthreads();
  float gi[64];
  #pragma unroll
  for (int k=0;k<64;k++) gi[k]=g_f[tid*64+k];
  float val=vb2[0];
  for (int j=0;j<64;j++){
    float s=b1s[j];
    #pragma unroll
    for (int k=0;k<64;k++) s+=gi[k]*w1[k*64+j];
    val += lrelu(s)*w2[j];
  }
  out[tid]=val;
}

extern "C" void kernel_launch(void* const* d_in, const int* in_sizes, int n_in,
                              void* d_out, int out_size, void* d_ws, size_t ws_size,
                              hipStream_t stream){
  const float* x    =(const float*)d_in[0];
  const float* ea   =(const float*)d_in[1];
  const float* uu   =(const float*)d_in[2];
  const float* eew  =(const float*)d_in[3];
  const float* eeb  =(const float*)d_in[4];
  const float* enw  =(const float*)d_in[5];
  const float* enb  =(const float*)d_in[6];
  const float* egw  =(const float*)d_in[7];
  const float* egb  =(const float*)d_in[8];
  const float* ew1  =(const float*)d_in[9];
  const float* eb1  =(const float*)d_in[10];
  const float* ew2  =(const float*)d_in[11];
  const float* eb2  =(const float*)d_in[12];
  const float* ew3  =(const float*)d_in[13];
  const float* eb3  =(const float*)d_in[14];
  const float* nw1  =(const float*)d_in[15];
  const float* nb1  =(const float*)d_in[16];
  const float* nw2  =(const float*)d_in[17];
  const float* nb2  =(const float*)d_in[18];
  const float* nw3  =(const float*)d_in[19];
  const float* nb3  =(const float*)d_in[20];
  const float* gw1  =(const float*)d_in[21];
  const float* gb1  =(const float*)d_in[22];
  const float* gw2  =(const float*)d_in[23];
  const float* gb2  =(const float*)d_in[24];
  const float* gw3  =(const float*)d_in[25];
  const float* gb3  =(const float*)d_in[26];
  const float* dw   =(const float*)d_in[27];
  const float* db   =(const float*)d_in[28];
  const float* vw1  =(const float*)d_in[29];
  const float* vb1  =(const float*)d_in[30];
  const float* vw2  =(const float*)d_in[31];
  const float* vb2  =(const float*)d_in[32];
  const int* eidx =(const int*)d_in[33];
  const int* batch=(const int*)d_in[34];

  char* ws=(char*)d_ws; size_t off=0;
  auto alloc=[&](size_t b)->char*{ char* p=ws+off; off=(off+b+255)&~(size_t)255; return p; };
  u16*   xh_b =(u16*)  alloc((size_t)NN*64*2);
  u16*   e_s  =(u16*)  alloc((size_t)EE*64*2);   // dest-sorted e features
  float* eagg =(float*)alloc((size_t)NN*64*4);
  float* xagg =(float*)alloc((size_t)BB*64*4);
  u16*   g_bb =(u16*)  alloc((size_t)BB*64*2);
  float* g_f  =(float*)alloc((size_t)BB*64*4);
  u16* ew1f=(u16*)alloc((size_t)PP*4096*16);
  u16* ew2f=(u16*)alloc((size_t)PP*2048*16);
  u16* ew3f=(u16*)alloc((size_t)PP*1024*16);
  u16* nw1f=(u16*)alloc((size_t)PP*3072*16);
  u16* nw2f=(u16*)alloc((size_t)PP*2048*16);
  u16* nw3f=(u16*)alloc((size_t)PP*1024*16);
  u16* gw1f=(u16*)alloc((size_t)PP*2048*16);
  u16* gw2f=(u16*)alloc((size_t)PP*2048*16);
  u16* gw3f=(u16*)alloc((size_t)PP*1024*16);
  int* hist =(int*)alloc((size_t)NN*4);
  int* offs =(int*)alloc((size_t)NN*4);
  int* perm =(int*)alloc((size_t)EE*4);
  int* dcols=(int*)alloc((size_t)EE*4);
  int* inv  =(int*)alloc((size_t)EE*4);
  float* out=(float*)d_out;

  // ---- counting sort of edges by destination (+ inverse perm) ----
  hipMemsetAsync(hist, 0, (size_t)NN*4, stream);
  k_hist<<<(EE+255)/256,256,0,stream>>>(eidx, hist);
  k_scan<<<1,1024,0,stream>>>(hist, offs);
  k_scatter<<<(EE+255)/256,256,0,stream>>>(eidx, offs, perm, dcols, inv);

  auto rp=[&](const float* W, u16* dst, int K, int Nn){
    int total = PP*(K/32)*(Nn/16)*64;
    k_repack<<<(total+255)/256,256,0,stream>>>(W,dst,K,Nn);
  };
  rp(ew1,ew1f,256,128); rp(ew2,ew2f,128,128); rp(ew3,ew3f,128,64);
  rp(nw1,nw1f,192,128); rp(nw2,nw2f,128,128); rp(nw3,nw3f,128,64);
  rp(gw1,gw1f,128,128); rp(gw2,gw2f,128,128); rp(gw3,gw3f,128,64);

  k_embed<true ><<<(EE+255)/256,256,0,stream>>>(ea, eew, eeb, e_s, EE, inv);
  k_embed<false><<<(NN+255)/256,256,0,stream>>>(x,  enw, enb, xh_b, NN, nullptr);
  k_embed_g<<<1,64,0,stream>>>(uu, egw, egb, g_bb, g_f);

  for (int p=0;p<PP;p++){
    hipMemsetAsync(eagg, 0, (size_t)NN*64*4, stream);
    hipMemsetAsync(xagg, 0, (size_t)BB*64*4, stream);
    if (p<PP-1)
      k_mlp<256,0,false><<<EE/64,256,0,stream>>>(xh_b,e_s,eagg,xagg,g_bb,g_f,eidx,batch,perm,dcols,
          (const uint4*)ew1f + (size_t)p*4096, (const uint4*)ew2f + (size_t)p*2048, (const uint4*)ew3f + (size_t)p*1024,
          eb1+p*128, eb2+p*128, eb3+p*64, dw, db, out);
    else
      k_mlp<256,0,true><<<EE/64,256,0,stream>>>(xh_b,e_s,eagg,xagg,g_bb,g_f,eidx,batch,perm,dcols,
          (const uint4*)ew1f + (size_t)p*4096, (const uint4*)ew2f + (size_t)p*2048, (const uint4*)ew3f + (size_t)p*1024,
          eb1+p*128, eb2+p*128, eb3+p*64, dw, db, out);
    k_mlp<192,1,false><<<(NN+63)/64,256,0,stream>>>(xh_b,e_s,eagg,xagg,g_bb,g_f,eidx,batch,perm,dcols,
        (const uint4*)nw1f + (size_t)p*3072, (const uint4*)nw2f + (size_t)p*2048, (const uint4*)nw3f + (size_t)p*1024,
        nb1+p*128, nb2+p*128, nb3+p*64, dw, db, out);
    k_mlp<128,2,false><<<1,256,0,stream>>>(xh_b,e_s,eagg,xagg,g_bb,g_f,eidx,batch,perm,dcols,
        (const uint4*)gw1f + (size_t)p*2048, (const uint4*)gw2f + (size_t)p*2048, (const uint4*)gw3f + (size_t)p*1024,
        gb1+p*128, gb2+p*128, gb3+p*64, dw, db, out);
  }
  k_value<<<1,64,0,stream>>>(g_f, vw1, vb1, vw2, vb2, out+EE);
}

// Round 8
// 1160.493 us; speedup vs baseline: 8.2429x; 1.0372x over previous
//
#include <hip/hip_runtime.h>
#include <hip/hip_bf16.h>
#include <stdint.h>

typedef unsigned short u16;
typedef unsigned int u32;
typedef short s16x8 __attribute__((ext_vector_type(8)));
typedef float f32x4 __attribute__((ext_vector_type(4)));

#define NN 50000
#define EE 800000
#define BB 64
#define PP 3

__device__ __forceinline__ float b2f(u16 x){ union{u32 u; float f;} c; c.u=((u32)x)<<16; return c.f; }
__device__ __forceinline__ u16 f2b(float v){ union{float f; u32 u;} c; c.f=v; u32 u=c.u; return (u16)((u + 0x7fffu + ((u>>16)&1u))>>16); }
__device__ __forceinline__ float lrelu(float v){ return v>0.f ? v : 0.01f*v; }
__device__ __forceinline__ f32x4 MFMA(s16x8 a, s16x8 b, f32x4 c){
  return __builtin_amdgcn_mfma_f32_16x16x32_bf16(a,b,c,0,0,0);
}

// bijective XCD-aware block swizzle (m204): consecutive output chunks land on one XCD
__device__ __forceinline__ int xcd_swz(int bid, int nwg){
  int q = nwg>>3, r = nwg&7;
  int x = bid&7, i = bid>>3;
  return (x<r ? x*(q+1) : r*(q+1)+(x-r)*q) + i;
}

// ---------------- counting sort of edges by destination ----------------
__global__ __launch_bounds__(256) void k_hist(const int* __restrict__ eidx, int* __restrict__ hist){
  int e = blockIdx.x*256 + threadIdx.x;
  if (e < EE) atomicAdd(&hist[eidx[EE+e]], 1);
}

__global__ __launch_bounds__(1024) void k_scan(const int* __restrict__ hist, int* __restrict__ offs){
  __shared__ int lsums[1024];
  const int tid = threadIdx.x;
  const int CH = 49; // 1024*49 = 50176 >= NN
  int base = tid*CH;
  int s = 0;
  for (int i=0;i<CH;i++){ int b=base+i; if (b<NN) s += hist[b]; }
  lsums[tid]=s; __syncthreads();
  for (int off=1; off<1024; off<<=1){
    int v = (tid>=off)? lsums[tid-off] : 0;
    __syncthreads();
    lsums[tid] += v;
    __syncthreads();
  }
  int run = (tid>0)? lsums[tid-1] : 0;
  for (int i=0;i<CH;i++){ int b=base+i; if (b<NN){ offs[b]=run; run+=hist[b]; } }
}

__global__ __launch_bounds__(256) void k_scatter(const int* __restrict__ eidx, int* __restrict__ offs,
                                                 int* __restrict__ perm, int* __restrict__ dcols,
                                                 int* __restrict__ inv){
  int e = blockIdx.x*256 + threadIdx.x;
  if (e >= EE) return;
  int col = eidx[EE+e];
  int pos = atomicAdd(&offs[col], 1);
  perm[pos] = e;
  dcols[pos] = col;
  inv[e] = pos;
}

// ---------------- weight repack: fp32 [P][K][N] row-major -> bf16 per-lane MFMA fragments
// frag element (p, kb, nb, lane, j) = W[p][kb*32 + (lane>>4)*8 + j][nb*16 + (lane&15)]
__global__ __launch_bounds__(256) void k_repack(const float* __restrict__ W, u16* __restrict__ out, int K, int Nn){
  int chunks_pp = (K/32)*(Nn/16)*64;
  int t = blockIdx.x*256 + threadIdx.x;
  if (t >= PP*chunks_pp) return;
  int p = t/chunks_pp, rem = t%chunks_pp;
  int NB = Nn/16;
  int kb = rem/(NB*64); int r2 = rem%(NB*64);
  int nb = r2/64; int l = r2&63;
  const float* Wp = W + (size_t)p*K*Nn;
  int k0 = kb*32 + ((l>>4)<<3), n = nb*16 + (l&15);
  u16 tmp[8];
  #pragma unroll
  for (int j=0;j<8;j++) tmp[j] = f2b(Wp[(size_t)(k0+j)*Nn + n]);
  *(uint4*)(out + (size_t)t*8) = *(uint4*)tmp;
}

// ---------------- embeddings: out[row] = lrelu(in[row,0:16] @ W[16,64] + b)  (fp32 in -> bf16 out)
// SCATTER: write to out[inv[row]] (edge features stored dest-sorted)
template<bool SCATTER>
__global__ __launch_bounds__(256) void k_embed(const float* __restrict__ in, const float* __restrict__ W,
                                               const float* __restrict__ b, u16* __restrict__ out, int nrows,
                                               const int* __restrict__ inv){
  __shared__ float wl[1024];
  __shared__ float bl[64];
  int tid = threadIdx.x;
  for (int i=tid;i<1024;i+=256) wl[i]=W[i];
  if (tid<64) bl[tid]=b[tid];
  __syncthreads();
  int row = blockIdx.x*256 + tid;
  if (row >= nrows) return;
  float inb[16];
  const float4* src4=(const float4*)(in + (size_t)row*16);
  #pragma unroll
  for (int q=0;q<4;q++){ float4 v=src4[q]; inb[q*4]=v.x; inb[q*4+1]=v.y; inb[q*4+2]=v.z; inb[q*4+3]=v.w; }
  float acc[64];
  #pragma unroll
  for (int j=0;j<64;j++) acc[j]=bl[j];
  #pragma unroll
  for (int k=0;k<16;k++){
    float a = inb[k];
    const float4* wr4 = (const float4*)(wl + k*64);
    #pragma unroll
    for (int j4=0;j4<16;j4++){
      float4 w4 = wr4[j4];
      acc[j4*4+0] += a*w4.x; acc[j4*4+1] += a*w4.y;
      acc[j4*4+2] += a*w4.z; acc[j4*4+3] += a*w4.w;
    }
  }
  u16 ob[64];
  #pragma unroll
  for (int j=0;j<64;j++) ob[j]=f2b(lrelu(acc[j]));
  int drow = SCATTER ? inv[row] : row;
  uint4* dst=(uint4*)(out + (size_t)drow*64);
  #pragma unroll
  for (int j=0;j<8;j++) dst[j]=((uint4*)ob)[j];
}

__global__ void k_embed_g(const float* __restrict__ in, const float* __restrict__ W, const float* __restrict__ b,
                          u16* __restrict__ g_b, float* __restrict__ g_f){
  __shared__ float wl[1024];
  __shared__ float bl[64];
  int tid = threadIdx.x; // 64 threads
  for (int i=tid;i<1024;i+=64) wl[i]=W[i];
  if (tid<64) bl[tid]=b[tid];
  __syncthreads();
  int row = tid;
  float inb[16];
  const float4* src4=(const float4*)(in + (size_t)row*16);
  #pragma unroll
  for (int q=0;q<4;q++){ float4 v=src4[q]; inb[q*4]=v.x; inb[q*4+1]=v.y; inb[q*4+2]=v.z; inb[q*4+3]=v.w; }
  float acc[64];
  #pragma unroll
  for (int j=0;j<64;j++) acc[j]=bl[j];
  #pragma unroll
  for (int k=0;k<16;k++){
    float a = inb[k];
    const float* wr = wl + k*64;
    #pragma unroll
    for (int j=0;j<64;j++) acc[j] += a*wr[j];
  }
  #pragma unroll
  for (int j=0;j<64;j++){
    float v = lrelu(acc[j]);
    g_f[row*64+j] = v;
    g_b[row*64+j] = f2b(v);
  }
}

// RMW helper: 16 contiguous bf16 += vals
__device__ __forceinline__ void rmw16(u16* p, const float* vals){
  uint4 q0=((uint4*)p)[0], q1=((uint4*)p)[1];
  const u16* h0=(const u16*)&q0; const u16* hq=(const u16*)&q1;
  u16 o[16];
  #pragma unroll
  for (int c=0;c<8;c++) o[c]=f2b(b2f(h0[c])+vals[c]);
  #pragma unroll
  for (int c=0;c<8;c++) o[8+c]=f2b(b2f(hq[c])+vals[8+c]);
  ((uint4*)p)[0]=*(uint4*)o; ((uint4*)p)[1]=*(uint4*)(o+8);
}

// ---------------- fused 3-layer MLP per 64 rows, weights in registers, waves N-sliced.
// Hidden buffers alias the gather buffer: h1=a0[0:16K], h2=a0[16K:32K], h3=a0[0:16K].
// Barriers: [1] gather, [1b] L1-reads done, [2] h1 ready, [3] h2 ready, [4] h3 ready.
// MODE 0: edge model (dest-sorted storage), MODE 1: node model, MODE 2: global model.
// LAST: fuse edge decoder (MODE 0, pass 3).
template<int K0, int MODE, bool LAST>
__global__ __launch_bounds__(256,4) void k_mlp(
    u16* __restrict__ xh_b, u16* __restrict__ e_b,   // e_b points at dest-sorted e storage
    float* __restrict__ eagg, float* __restrict__ xagg,
    u16* __restrict__ g_b, float* __restrict__ g_f,
    const int* __restrict__ eidx, const int* __restrict__ batch,
    const int* __restrict__ perm, const int* __restrict__ dcols,
    const uint4* __restrict__ w1f, const uint4* __restrict__ w2f, const uint4* __restrict__ w3f,
    const float* __restrict__ b1, const float* __restrict__ b2, const float* __restrict__ b3,
    const float* __restrict__ dw, const float* __restrict__ db, float* __restrict__ outp)
{
  constexpr int KB  = K0/32;
  constexpr int RS  = K0*2;   // a0 row stride bytes
  constexpr int A0SZ = (64*RS > 32768) ? 64*RS : 32768;
  __shared__ __align__(16) char a0[A0SZ];
  __shared__ int s_edge[64];
  __shared__ int s_dcol[64];
  char* h1 = a0;            // bf16 256B rows
  char* h2 = a0 + 16384;    // bf16 256B rows
  char* h3 = a0;            // fp32 256B rows

  const int tid  = threadIdx.x;
  const int wave = tid>>6, lane = tid&63;
  const int rowbase = (MODE==2 ? blockIdx.x : xcd_swz(blockIdx.x, gridDim.x))*64;
  const int lrow = lane&15;                 // row-within-16 for fragment reads
  const int lsw  = (lane&7)<<4;             // swizzle (row&7)<<4, rb-independent
  const int aoff = (lane>>4)*16;            // k-chunk byte offset within 64B
  const int qc   = (lane>>4)*4;             // out-col quad base

  // ---------- load W1 fragments into registers (N-sliced: this wave's 2 nb) ----------
  s16x8 wA[KB][2];
  #pragma unroll
  for (int kb=0;kb<KB;kb++){
    #pragma unroll
    for (int j=0;j<2;j++)
      wA[kb][j] = *(const s16x8*)(w1f + (size_t)(kb*8 + wave*2 + j)*64 + lane);
  }

  // ---------- gather input rows into swizzled a0 ----------
  {
    const int r = tid>>2, s = tid&3;
    char* drow = a0 + r*RS;
    const int sw = (r&7)<<4;
    if (MODE==0){
      const int slot = rowbase + r;
      const int edge = perm[slot];
      if (s==0){ s_edge[r]=edge; s_dcol[r]=dcols[slot]; }
      const int er = eidx[edge], ec = eidx[EE+edge];
      const u16* src = (s==0)? xh_b + (size_t)er*64
                     : (s==1)? xh_b + (size_t)ec*64
                     : (s==2)? e_b  + (size_t)slot*64          // dest-sorted: contiguous
                     :         g_b  + (size_t)batch[er]*64;
      const uint4* s4=(const uint4*)src;
      #pragma unroll
      for (int j=0;j<8;j++)
        *(uint4*)(drow + ((s*128 + j*16) ^ sw)) = s4[j];
    } else if (MODE==1){
      const int node = rowbase + r;
      const bool ok = node < NN;
      if (s==0){
        const uint4* s4=(const uint4*)(xh_b + (size_t)node*64);
        #pragma unroll
        for (int j=0;j<8;j++){ uint4 v={0,0,0,0}; if (ok) v=s4[j];
          *(uint4*)(drow + ((j*16) ^ sw)) = v; }
      } else if (s==1){
        const float4* s4=(const float4*)(eagg + (size_t)node*64);
        #pragma unroll
        for (int j=0;j<8;j++){
          u16 tmp[8]={0,0,0,0,0,0,0,0};
          if (ok){ float4 lo=s4[2*j], hi=s4[2*j+1];
            tmp[0]=f2b(lo.x);tmp[1]=f2b(lo.y);tmp[2]=f2b(lo.z);tmp[3]=f2b(lo.w);
            tmp[4]=f2b(hi.x);tmp[5]=f2b(hi.y);tmp[6]=f2b(hi.z);tmp[7]=f2b(hi.w); }
          *(uint4*)(drow + ((128 + j*16) ^ sw)) = *(uint4*)tmp;
        }
      } else if (s==2){
        int bidx = ok ? batch[node] : 0;
        const uint4* s4=(const uint4*)(g_b + (size_t)bidx*64);
        #pragma unroll
        for (int j=0;j<8;j++){ uint4 v={0,0,0,0}; if (ok) v=s4[j];
          *(uint4*)(drow + ((256 + j*16) ^ sw)) = v; }
      }
    } else { // GLOB: 64 graphs, all valid
      if (s==0){
        const uint4* s4=(const uint4*)(g_b + (size_t)r*64);
        #pragma unroll
        for (int j=0;j<8;j++) *(uint4*)(drow + ((j*16) ^ sw)) = s4[j];
      } else if (s==1){
        const float4* s4=(const float4*)(xagg + (size_t)r*64);
        #pragma unroll
        for (int j=0;j<8;j++){
          u16 tmp[8];
          float4 lo=s4[2*j], hi=s4[2*j+1];
          tmp[0]=f2b(lo.x);tmp[1]=f2b(lo.y);tmp[2]=f2b(lo.z);tmp[3]=f2b(lo.w);
          tmp[4]=f2b(hi.x);tmp[5]=f2b(hi.y);tmp[6]=f2b(hi.z);tmp[7]=f2b(hi.w);
          *(uint4*)(drow + ((128 + j*16) ^ sw)) = *(uint4*)tmp;
        }
      }
    }
  }
  __syncthreads();   // [1] gather visible

  // ---------- layer 1 (K0 -> 128): acc[rb][j] = W-slice x all 64 rows ----------
  f32x4 acc[4][2];
  #pragma unroll
  for (int rb=0;rb<4;rb++){ acc[rb][0]=f32x4{0,0,0,0}; acc[rb][1]=f32x4{0,0,0,0}; }
  #pragma unroll
  for (int kb=0;kb<KB;kb++){
    #pragma unroll
    for (int rb=0;rb<4;rb++){
      s16x8 af = *(const s16x8*)(a0 + (rb*16+lrow)*RS + ((kb*64 + aoff) ^ lsw));
      acc[rb][0] = MFMA(wA[kb][0], af, acc[rb][0]);
      acc[rb][1] = MFMA(wA[kb][1], af, acc[rb][1]);
    }
  }

  // load W2 fragments (latency hidden under epilogue + barrier)
  s16x8 wB[4][2];
  #pragma unroll
  for (int kb=0;kb<4;kb++){
    #pragma unroll
    for (int j=0;j<2;j++)
      wB[kb][j] = *(const s16x8*)(w2f + (size_t)(kb*8 + wave*2 + j)*64 + lane);
  }
  __syncthreads();   // [1b] all L1 reads of a0 done

  // epilogue 1 -> h1 (bf16, packed b64 stores; row = rb*16+lrow, cols = wave*32+j*16+qc..+3)
  #pragma unroll
  for (int j=0;j<2;j++){
    const float4 bs = *(const float4*)(b1 + wave*32 + j*16 + qc);
    #pragma unroll
    for (int rb=0;rb<4;rb++){
      int row = rb*16 + lrow;
      int c2 = (wave*32 + j*16 + qc)*2;
      u16 t0=f2b(lrelu(acc[rb][j][0]+bs.x)), t1=f2b(lrelu(acc[rb][j][1]+bs.y));
      u16 t2=f2b(lrelu(acc[rb][j][2]+bs.z)), t3=f2b(lrelu(acc[rb][j][3]+bs.w));
      uint2 pk = make_uint2((u32)t0 | ((u32)t1<<16), (u32)t2 | ((u32)t3<<16));
      *(uint2*)(h1 + row*256 + (c2 ^ ((row&7)<<4))) = pk;
    }
  }
  __syncthreads();   // [2] h1 ready

  // ---------- layer 2 (128 -> 128) ----------
  f32x4 acc2[4][2];
  #pragma unroll
  for (int rb=0;rb<4;rb++){ acc2[rb][0]=f32x4{0,0,0,0}; acc2[rb][1]=f32x4{0,0,0,0}; }
  #pragma unroll
  for (int kb=0;kb<4;kb++){
    #pragma unroll
    for (int rb=0;rb<4;rb++){
      s16x8 af = *(const s16x8*)(h1 + (rb*16+lrow)*256 + ((kb*64 + aoff) ^ lsw));
      acc2[rb][0] = MFMA(wB[kb][0], af, acc2[rb][0]);
      acc2[rb][1] = MFMA(wB[kb][1], af, acc2[rb][1]);
    }
  }

  // load W3 fragments (N=64: 1 nb per wave)
  s16x8 wC[4];
  #pragma unroll
  for (int kb=0;kb<4;kb++)
    wC[kb] = *(const s16x8*)(w3f + (size_t)(kb*4 + wave)*64 + lane);

  // epilogue 2 -> h2 (disjoint from h1; other waves may still read h1)
  #pragma unroll
  for (int j=0;j<2;j++){
    const float4 bs = *(const float4*)(b2 + wave*32 + j*16 + qc);
    #pragma unroll
    for (int rb=0;rb<4;rb++){
      int row = rb*16 + lrow;
      int c2 = (wave*32 + j*16 + qc)*2;
      u16 t0=f2b(lrelu(acc2[rb][j][0]+bs.x)), t1=f2b(lrelu(acc2[rb][j][1]+bs.y));
      u16 t2=f2b(lrelu(acc2[rb][j][2]+bs.z)), t3=f2b(lrelu(acc2[rb][j][3]+bs.w));
      uint2 pk = make_uint2((u32)t0 | ((u32)t1<<16), (u32)t2 | ((u32)t3<<16));
      *(uint2*)(h2 + row*256 + (c2 ^ ((row&7)<<4))) = pk;
    }
  }
  __syncthreads();   // [3] h2 ready (and all h1 reads done)

  // ---------- layer 3 (128 -> 64, no activation) ----------
  f32x4 acc3[4];
  #pragma unroll
  for (int rb=0;rb<4;rb++) acc3[rb]=f32x4{0,0,0,0};
  #pragma unroll
  for (int kb=0;kb<4;kb++){
    #pragma unroll
    for (int rb=0;rb<4;rb++){
      s16x8 af = *(const s16x8*)(h2 + (rb*16+lrow)*256 + ((kb*64 + aoff) ^ lsw));
      acc3[rb] = MFMA(wC[kb], af, acc3[rb]);
    }
  }
  // epilogue 3 -> h3 (= h1 region, dead; disjoint from h2 which others may still read)
  {
    const float4 b3v = *(const float4*)(b3 + wave*16 + qc);
    #pragma unroll
    for (int rb=0;rb<4;rb++){
      int row = rb*16 + lrow;
      int c4 = (wave*16 + qc)*4;
      float4 o = make_float4(acc3[rb][0]+b3v.x, acc3[rb][1]+b3v.y, acc3[rb][2]+b3v.z, acc3[rb][3]+b3v.w);
      *(float4*)(h3 + row*256 + (c4 ^ ((row&7)<<4))) = o;
    }
  }
  __syncthreads();   // [4] h3 ready

  // ---------- finisher ----------
  const int r2 = tid>>2, cs = (tid&3)*16;
  const int rsw2 = (r2&7)<<4;
  if (MODE==0){
    const int slot = rowbase + r2;
    float vals[16];
    #pragma unroll
    for (int c=0;c<16;c++) vals[c]=*(const float*)(h3 + r2*256 + (((cs+c)*4)^rsw2));
    if (LAST){
      // e += e_new (dest-sorted storage), fused decode into original edge order
      const int edge = s_edge[r2];
      u16* p = e_b + (size_t)slot*64 + cs;
      uint4 q0=((uint4*)p)[0], q1=((uint4*)p)[1];
      const u16* h0=(const u16*)&q0; const u16* hq=(const u16*)&q1;
      float dwl[16];
      const float4* dw4 = (const float4*)(dw + cs);
      #pragma unroll
      for (int q=0;q<4;q++){ float4 v=dw4[q]; dwl[q*4]=v.x; dwl[q*4+1]=v.y; dwl[q*4+2]=v.z; dwl[q*4+3]=v.w; }
      u16 o[16]; float part=0.f;
      #pragma unroll
      for (int c=0;c<8;c++){ u16 nb16=f2b(b2f(h0[c])+vals[c]); o[c]=nb16; part += b2f(nb16)*dwl[c]; }
      #pragma unroll
      for (int c=0;c<8;c++){ u16 nb16=f2b(b2f(hq[c])+vals[8+c]); o[8+c]=nb16; part += b2f(nb16)*dwl[8+c]; }
      ((uint4*)p)[0]=*(uint4*)o; ((uint4*)p)[1]=*(uint4*)(o+8);
      part += __shfl_xor(part,1);
      part += __shfl_xor(part,2);
      if ((tid&3)==0) outp[edge] = part + db[0];
    } else {
      rmw16(e_b + (size_t)slot*64 + cs, vals);       // e += e_new, coalesced
    }
    // run-length-reduced segment_sum(e_new, dcol) — slots sorted by dcol
    const int col64 = tid&63, rg = tid>>6;
    float ssum = 0.f; int cur = -1;
    #pragma unroll
    for (int rr=0;rr<16;rr++){
      int row = rg*16+rr;
      int gid = s_dcol[row];
      float v = *(const float*)(h3 + row*256 + ((col64*4) ^ ((row&7)<<4)));
      if (gid != cur){ if (cur>=0) unsafeAtomicAdd(eagg + (size_t)cur*64 + col64, ssum); ssum=0.f; cur=gid; }
      ssum += v;
    }
    if (cur>=0) unsafeAtomicAdd(eagg + (size_t)cur*64 + col64, ssum);
  } else if (MODE==1){
    const int node = rowbase + r2;
    if (node < NN){
      float vals[16];
      #pragma unroll
      for (int c=0;c<16;c++) vals[c]=*(const float*)(h3 + r2*256 + (((cs+c)*4)^rsw2));
      rmw16(xh_b + (size_t)node*64 + cs, vals);             // xh += x_new
    }
    // per-graph reduction of x_new (batch sorted -> few runs per block)
    const int col = tid&63, rg = tid>>6;
    float s = 0.f; int cur = -1;
    for (int rr=0;rr<16;rr++){
      int row = rg*16+rr; int nd = rowbase+row;
      int gid = (nd<NN) ? batch[nd] : -1;
      float v = *(const float*)(h3 + row*256 + ((col*4) ^ ((row&7)<<4)));
      if (gid != cur){ if (cur>=0) unsafeAtomicAdd(xagg + cur*64 + col, s); s=0.f; cur=gid; }
      if (gid>=0) s += v;
    }
    if (cur>=0) unsafeAtomicAdd(xagg + cur*64 + col, s);
  } else {
    float vals[16];
    #pragma unroll
    for (int c=0;c<16;c++) vals[c]=*(const float*)(h3 + r2*256 + (((cs+c)*4)^rsw2));
    #pragma unroll
    for (int c=0;c<16;c++){
      int idx = r2*64 + cs + c;
      float nv = g_f[idx] + vals[c];
      g_f[idx] = nv; g_b[idx] = f2b(nv);     // g += g_new (fp32 master + bf16 copy)
    }
  }
}

// ---------------- value head: lrelu(g @ vw1 + vb1) @ vw2 + vb2  (fp32 out)
__global__ void k_value(const float* __restrict__ g_f, const float* __restrict__ vw1, const float* __restrict__ vb1,
                        const float* __restrict__ vw2, const float* __restrict__ vb2, float* __restrict__ out){
  __shared__ float w1[4096];
  __shared__ float b1s[64];
  __shared__ float w2[64];
  int tid=threadIdx.x; // 64
  for (int i=tid;i<4096;i+=64) w1[i]=vw1[i];
  if (tid<64){ b1s[tid]=vb1[tid]; w2[tid]=vw2[tid]; }
  __syncthreads();
  float gi[64];
  #pragma unroll
  for (int k=0;k<64;k++) gi[k]=g_f[tid*64+k];
  float val=vb2[0];
  for (int j=0;j<64;j++){
    float s=b1s[j];
    #pragma unroll
    for (int k=0;k<64;k++) s+=gi[k]*w1[k*64+j];
    val += lrelu(s)*w2[j];
  }
  out[tid]=val;
}

extern "C" void kernel_launch(void* const* d_in, const int* in_sizes, int n_in,
                              void* d_out, int out_size, void* d_ws, size_t ws_size,
                              hipStream_t stream){
  const float* x    =(const float*)d_in[0];
  const float* ea   =(const float*)d_in[1];
  const float* uu   =(const float*)d_in[2];
  const float* eew  =(const float*)d_in[3];
  const float* eeb  =(const float*)d_in[4];
  const float* enw  =(const float*)d_in[5];
  const float* enb  =(const float*)d_in[6];
  const float* egw  =(const float*)d_in[7];
  const float* egb  =(const float*)d_in[8];
  const float* ew1  =(const float*)d_in[9];
  const float* eb1  =(const float*)d_in[10];
  const float* ew2  =(const float*)d_in[11];
  const float* eb2  =(const float*)d_in[12];
  const float* ew3  =(const float*)d_in[13];
  const float* eb3  =(const float*)d_in[14];
  const float* nw1  =(const float*)d_in[15];
  const float* nb1  =(const float*)d_in[16];
  const float* nw2  =(const float*)d_in[17];
  const float* nb2  =(const float*)d_in[18];
  const float* nw3  =(const float*)d_in[19];
  const float* nb3  =(const float*)d_in[20];
  const float* gw1  =(const float*)d_in[21];
  const float* gb1  =(const float*)d_in[22];
  const float* gw2  =(const float*)d_in[23];
  const float* gb2  =(const float*)d_in[24];
  const float* gw3  =(const float*)d_in[25];
  const float* gb3  =(const float*)d_in[26];
  const float* dw   =(const float*)d_in[27];
  const float* db   =(const float*)d_in[28];
  const float* vw1  =(const float*)d_in[29];
  const float* vb1  =(const float*)d_in[30];
  const float* vw2  =(const float*)d_in[31];
  const float* vb2  =(const float*)d_in[32];
  const int* eidx =(const int*)d_in[33];
  const int* batch=(const int*)d_in[34];

  char* ws=(char*)d_ws; size_t off=0;
  auto alloc=[&](size_t b)->char*{ char* p=ws+off; off=(off+b+255)&~(size_t)255; return p; };
  u16*   xh_b =(u16*)  alloc((size_t)NN*64*2);
  u16*   e_s  =(u16*)  alloc((size_t)EE*64*2);   // dest-sorted e features
  float* eagg =(float*)alloc((size_t)NN*64*4);
  float* xagg =(float*)alloc((size_t)BB*64*4);
  u16*   g_bb =(u16*)  alloc((size_t)BB*64*2);
  float* g_f  =(float*)alloc((size_t)BB*64*4);
  u16* ew1f=(u16*)alloc((size_t)PP*4096*16);
  u16* ew2f=(u16*)alloc((size_t)PP*2048*16);
  u16* ew3f=(u16*)alloc((size_t)PP*1024*16);
  u16* nw1f=(u16*)alloc((size_t)PP*3072*16);
  u16* nw2f=(u16*)alloc((size_t)PP*2048*16);
  u16* nw3f=(u16*)alloc((size_t)PP*1024*16);
  u16* gw1f=(u16*)alloc((size_t)PP*2048*16);
  u16* gw2f=(u16*)alloc((size_t)PP*2048*16);
  u16* gw3f=(u16*)alloc((size_t)PP*1024*16);
  int* hist =(int*)alloc((size_t)NN*4);
  int* offs =(int*)alloc((size_t)NN*4);
  int* perm =(int*)alloc((size_t)EE*4);
  int* dcols=(int*)alloc((size_t)EE*4);
  int* inv  =(int*)alloc((size_t)EE*4);
  float* out=(float*)d_out;

  // ---- counting sort of edges by destination (+ inverse perm) ----
  hipMemsetAsync(hist, 0, (size_t)NN*4, stream);
  k_hist<<<(EE+255)/256,256,0,stream>>>(eidx, hist);
  k_scan<<<1,1024,0,stream>>>(hist, offs);
  k_scatter<<<(EE+255)/256,256,0,stream>>>(eidx, offs, perm, dcols, inv);

  auto rp=[&](const float* W, u16* dst, int K, int Nn){
    int total = PP*(K/32)*(Nn/16)*64;
    k_repack<<<(total+255)/256,256,0,stream>>>(W,dst,K,Nn);
  };
  rp(ew1,ew1f,256,128); rp(ew2,ew2f,128,128); rp(ew3,ew3f,128,64);
  rp(nw1,nw1f,192,128); rp(nw2,nw2f,128,128); rp(nw3,nw3f,128,64);
  rp(gw1,gw1f,128,128); rp(gw2,gw2f,128,128); rp(gw3,gw3f,128,64);

  k_embed<true ><<<(EE+255)/256,256,0,stream>>>(ea, eew, eeb, e_s, EE, inv);
  k_embed<false><<<(NN+255)/256,256,0,stream>>>(x,  enw, enb, xh_b, NN, nullptr);
  k_embed_g<<<1,64,0,stream>>>(uu, egw, egb, g_bb, g_f);

  for (int p=0;p<PP;p++){
    hipMemsetAsync(eagg, 0, (size_t)NN*64*4, stream);
    hipMemsetAsync(xagg, 0, (size_t)BB*64*4, stream);
    if (p<PP-1)
      k_mlp<256,0,false><<<EE/64,256,0,stream>>>(xh_b,e_s,eagg,xagg,g_bb,g_f,eidx,batch,perm,dcols,
          (const uint4*)ew1f + (size_t)p*4096, (const uint4*)ew2f + (size_t)p*2048, (const uint4*)ew3f + (size_t)p*1024,
          eb1+p*128, eb2+p*128, eb3+p*64, dw, db, out);
    else
      k_mlp<256,0,true><<<EE/64,256,0,stream>>>(xh_b,e_s,eagg,xagg,g_bb,g_f,eidx,batch,perm,dcols,
          (const uint4*)ew1f + (size_t)p*4096, (const uint4*)ew2f + (size_t)p*2048, (const uint4*)ew3f + (size_t)p*1024,
          eb1+p*128, eb2+p*128, eb3+p*64, dw, db, out);
    k_mlp<192,1,false><<<(NN+63)/64,256,0,stream>>>(xh_b,e_s,eagg,xagg,g_bb,g_f,eidx,batch,perm,dcols,
        (const uint4*)nw1f + (size_t)p*3072, (const uint4*)nw2f + (size_t)p*2048, (const uint4*)nw3f + (size_t)p*1024,
        nb1+p*128, nb2+p*128, nb3+p*64, dw, db, out);
    k_mlp<128,2,false><<<1,256,0,stream>>>(xh_b,e_s,eagg,xagg,g_bb,g_f,eidx,batch,perm,dcols,
        (const uint4*)gw1f + (size_t)p*2048, (const uint4*)gw2f + (size_t)p*2048, (const uint4*)gw3f + (size_t)p*1024,
        gb1+p*128, gb2+p*128, gb3+p*64, dw, db, out);
  }
  k_value<<<1,64,0,stream>>>(g_f, vw1, vb1, vw2, vb2, out+EE);
}

// Round 9
// 1112.709 us; speedup vs baseline: 8.5969x; 1.0429x over previous
//
#include <hip/hip_runtime.h>
#include <hip/hip_bf16.h>
#include <stdint.h>

typedef unsigned short u16;
typedef unsigned int u32;
typedef short s16x8 __attribute__((ext_vector_type(8)));
typedef float f32x4 __attribute__((ext_vector_type(4)));

#define NN 50000
#define EE 800000
#define BB 64
#define PP 3

__device__ __forceinline__ float b2f(u16 x){ union{u32 u; float f;} c; c.u=((u32)x)<<16; return c.f; }
__device__ __forceinline__ u16 f2b(float v){ union{float f; u32 u;} c; c.f=v; u32 u=c.u; return (u16)((u + 0x7fffu + ((u>>16)&1u))>>16); }
__device__ __forceinline__ float lrelu(float v){ return v>0.f ? v : 0.01f*v; }
__device__ __forceinline__ f32x4 MFMA(s16x8 a, s16x8 b, f32x4 c){
  return __builtin_amdgcn_mfma_f32_16x16x32_bf16(a,b,c,0,0,0);
}

// bijective XCD-aware block swizzle (m204)
__device__ __forceinline__ int xcd_swz(int bid, int nwg){
  int q = nwg>>3, r = nwg&7;
  int x = bid&7, i = bid>>3;
  return (x<r ? x*(q+1) : r*(q+1)+(x-r)*q) + i;
}

// ---------------- counting sort of edges by destination ----------------
__global__ __launch_bounds__(256) void k_hist(const int* __restrict__ eidx, int* __restrict__ hist){
  int e = blockIdx.x*256 + threadIdx.x;
  if (e < EE) atomicAdd(&hist[eidx[EE+e]], 1);
}

__global__ __launch_bounds__(1024) void k_scan(const int* __restrict__ hist, int* __restrict__ offs){
  __shared__ int lsums[1024];
  const int tid = threadIdx.x;
  const int CH = 49; // 1024*49 = 50176 >= NN
  int base = tid*CH;
  int s = 0;
  for (int i=0;i<CH;i++){ int b=base+i; if (b<NN) s += hist[b]; }
  lsums[tid]=s; __syncthreads();
  for (int off=1; off<1024; off<<=1){
    int v = (tid>=off)? lsums[tid-off] : 0;
    __syncthreads();
    lsums[tid] += v;
    __syncthreads();
  }
  int run = (tid>0)? lsums[tid-1] : 0;
  for (int i=0;i<CH;i++){ int b=base+i; if (b<NN){ offs[b]=run; run+=hist[b]; } }
}

// sorted gather indices: rows_s = src node, gbs = batch[src], dcols = dest node
__global__ __launch_bounds__(256) void k_scatter(const int* __restrict__ eidx, int* __restrict__ offs,
                                                 int* __restrict__ perm, int* __restrict__ dcols,
                                                 int* __restrict__ inv, int* __restrict__ rows_s,
                                                 int* __restrict__ gbs, const int* __restrict__ batch){
  int e = blockIdx.x*256 + threadIdx.x;
  if (e >= EE) return;
  int col = eidx[EE+e];
  int er  = eidx[e];
  int pos = atomicAdd(&offs[col], 1);
  perm[pos] = e;
  dcols[pos] = col;
  inv[e] = pos;
  rows_s[pos] = er;
  gbs[pos] = batch[er];
}

// ---------------- weight repack: fp32 [P][K][N] row-major -> bf16 per-lane MFMA fragments
__global__ __launch_bounds__(256) void k_repack(const float* __restrict__ W, u16* __restrict__ out, int K, int Nn){
  int chunks_pp = (K/32)*(Nn/16)*64;
  int t = blockIdx.x*256 + threadIdx.x;
  if (t >= PP*chunks_pp) return;
  int p = t/chunks_pp, rem = t%chunks_pp;
  int NB = Nn/16;
  int kb = rem/(NB*64); int r2 = rem%(NB*64);
  int nb = r2/64; int l = r2&63;
  const float* Wp = W + (size_t)p*K*Nn;
  int k0 = kb*32 + ((l>>4)<<3), n = nb*16 + (l&15);
  u16 tmp[8];
  #pragma unroll
  for (int j=0;j<8;j++) tmp[j] = f2b(Wp[(size_t)(k0+j)*Nn + n]);
  *(uint4*)(out + (size_t)t*8) = *(uint4*)tmp;
}

// ---------------- embeddings (fp32 in -> bf16 out); SCATTER: out[inv[row]]
template<bool SCATTER>
__global__ __launch_bounds__(256) void k_embed(const float* __restrict__ in, const float* __restrict__ W,
                                               const float* __restrict__ b, u16* __restrict__ out, int nrows,
                                               const int* __restrict__ inv){
  __shared__ float wl[1024];
  __shared__ float bl[64];
  int tid = threadIdx.x;
  for (int i=tid;i<1024;i+=256) wl[i]=W[i];
  if (tid<64) bl[tid]=b[tid];
  __syncthreads();
  int row = blockIdx.x*256 + tid;
  if (row >= nrows) return;
  float inb[16];
  const float4* src4=(const float4*)(in + (size_t)row*16);
  #pragma unroll
  for (int q=0;q<4;q++){ float4 v=src4[q]; inb[q*4]=v.x; inb[q*4+1]=v.y; inb[q*4+2]=v.z; inb[q*4+3]=v.w; }
  float acc[64];
  #pragma unroll
  for (int j=0;j<64;j++) acc[j]=bl[j];
  #pragma unroll
  for (int k=0;k<16;k++){
    float a = inb[k];
    const float4* wr4 = (const float4*)(wl + k*64);
    #pragma unroll
    for (int j4=0;j4<16;j4++){
      float4 w4 = wr4[j4];
      acc[j4*4+0] += a*w4.x; acc[j4*4+1] += a*w4.y;
      acc[j4*4+2] += a*w4.z; acc[j4*4+3] += a*w4.w;
    }
  }
  u16 ob[64];
  #pragma unroll
  for (int j=0;j<64;j++) ob[j]=f2b(lrelu(acc[j]));
  int drow = SCATTER ? inv[row] : row;
  uint4* dst=(uint4*)(out + (size_t)drow*64);
  #pragma unroll
  for (int j=0;j<8;j++) dst[j]=((uint4*)ob)[j];
}

__global__ void k_embed_g(const float* __restrict__ in, const float* __restrict__ W, const float* __restrict__ b,
                          u16* __restrict__ g_b, float* __restrict__ g_f){
  __shared__ float wl[1024];
  __shared__ float bl[64];
  int tid = threadIdx.x; // 64 threads
  for (int i=tid;i<1024;i+=64) wl[i]=W[i];
  if (tid<64) bl[tid]=b[tid];
  __syncthreads();
  int row = tid;
  float inb[16];
  const float4* src4=(const float4*)(in + (size_t)row*16);
  #pragma unroll
  for (int q=0;q<4;q++){ float4 v=src4[q]; inb[q*4]=v.x; inb[q*4+1]=v.y; inb[q*4+2]=v.z; inb[q*4+3]=v.w; }
  float acc[64];
  #pragma unroll
  for (int j=0;j<64;j++) acc[j]=bl[j];
  #pragma unroll
  for (int k=0;k<16;k++){
    float a = inb[k];
    const float* wr = wl + k*64;
    #pragma unroll
    for (int j=0;j<64;j++) acc[j] += a*wr[j];
  }
  #pragma unroll
  for (int j=0;j<64;j++){
    float v = lrelu(acc[j]);
    g_f[row*64+j] = v;
    g_b[row*64+j] = f2b(v);
  }
}

// ---------------- fused 3-layer MLP per 64 rows, weights in registers, waves N-sliced.
// Quarter-split gather: thread (r,s) loads its own 32B of each source; residual source
// quarters carried in registers -> finisher is WRITE-ONLY (no global re-read).
// LDS = 32KB exactly: a0 gather (<=32KB), h1=a0[0:16K], h2=a0[16K:32K], h3=a0[0:16K].
template<int K0, int MODE, bool LAST>
__global__ __launch_bounds__(256,5) void k_mlp(
    u16* __restrict__ xh_b, u16* __restrict__ e_b,   // e_b = dest-sorted e storage
    float* __restrict__ eagg, float* __restrict__ xagg,
    u16* __restrict__ g_b, float* __restrict__ g_f,
    const int* __restrict__ batch,
    const int* __restrict__ perm, const int* __restrict__ dcols,
    const int* __restrict__ rows_s, const int* __restrict__ gbs,
    const uint4* __restrict__ w1f, const uint4* __restrict__ w2f, const uint4* __restrict__ w3f,
    const float* __restrict__ b1, const float* __restrict__ b2, const float* __restrict__ b3,
    const float* __restrict__ dw, const float* __restrict__ db, float* __restrict__ outp)
{
  constexpr int KB  = K0/32;
  constexpr int RS  = K0*2;   // a0 row stride bytes
  __shared__ __align__(16) char a0[32768];
  char* h1 = a0;            // bf16 256B rows
  char* h2 = a0 + 16384;    // bf16 256B rows
  char* h3 = a0;            // fp32 256B rows

  const int tid  = threadIdx.x;
  const int wave = tid>>6, lane = tid&63;
  const int rowbase = (MODE==2 ? blockIdx.x : xcd_swz(blockIdx.x, gridDim.x))*64;
  const int lrow = lane&15;
  const int lsw  = (lane&7)<<4;
  const int aoff = (lane>>4)*16;
  const int qc   = (lane>>4)*4;

  // residual-source quarter carried in registers (e for MODE0, xh for MODE1)
  uint4 old0 = {0,0,0,0}, old1 = {0,0,0,0};

  // ---------- load W1 fragments into registers (N-sliced: this wave's 2 nb) ----------
  s16x8 wA[KB][2];
  #pragma unroll
  for (int kb=0;kb<KB;kb++){
    #pragma unroll
    for (int j=0;j<2;j++)
      wA[kb][j] = *(const s16x8*)(w1f + (size_t)(kb*8 + wave*2 + j)*64 + lane);
  }

  // ---------- gather: quarter-split, swizzled a0 ----------
  {
    const int r = tid>>2, s = tid&3;
    char* drow = a0 + r*RS;
    const int sw = (r&7)<<4;
    const int base = s*32;
    if (MODE==0){
      const int slot = rowbase + r;
      const int er = rows_s[slot];   // coalesced
      const int ec = dcols[slot];    // coalesced (dest node)
      const int gb = gbs[slot];      // coalesced
      const uint4* p0=(const uint4*)(xh_b + (size_t)er*64 + s*16);
      const uint4* p1=(const uint4*)(xh_b + (size_t)ec*64 + s*16);
      const uint4* p2=(const uint4*)(e_b  + (size_t)slot*64 + s*16);
      const uint4* p3=(const uint4*)(g_b  + (size_t)gb*64 + s*16);
      uint4 a_=p0[0], b_=p0[1], c_=p1[0], d_=p1[1];
      old0=p2[0]; old1=p2[1];
      uint4 g0=p3[0], g1=p3[1];
      *(uint4*)(drow + ((  0+base   ) ^ sw)) = a_;   *(uint4*)(drow + ((  0+base+16) ^ sw)) = b_;
      *(uint4*)(drow + ((128+base   ) ^ sw)) = c_;   *(uint4*)(drow + ((128+base+16) ^ sw)) = d_;
      *(uint4*)(drow + ((256+base   ) ^ sw)) = old0; *(uint4*)(drow + ((256+base+16) ^ sw)) = old1;
      *(uint4*)(drow + ((384+base   ) ^ sw)) = g0;   *(uint4*)(drow + ((384+base+16) ^ sw)) = g1;
    } else if (MODE==1){
      const int node = rowbase + r;
      const bool ok = node < NN;
      uint4 z={0,0,0,0};
      uint4 g0=z, g1=z;
      u16 t[16]={0,0,0,0,0,0,0,0,0,0,0,0,0,0,0,0};
      if (ok){
        const uint4* p0=(const uint4*)(xh_b + (size_t)node*64 + s*16);
        old0=p0[0]; old1=p0[1];
        const float4* p1=(const float4*)(eagg + (size_t)node*64 + s*16);
        float4 f0=p1[0], f1=p1[1], f2v=p1[2], f3=p1[3];
        t[0]=f2b(f0.x); t[1]=f2b(f0.y); t[2]=f2b(f0.z); t[3]=f2b(f0.w);
        t[4]=f2b(f1.x); t[5]=f2b(f1.y); t[6]=f2b(f1.z); t[7]=f2b(f1.w);
        t[8]=f2b(f2v.x); t[9]=f2b(f2v.y); t[10]=f2b(f2v.z); t[11]=f2b(f2v.w);
        t[12]=f2b(f3.x); t[13]=f2b(f3.y); t[14]=f2b(f3.z); t[15]=f2b(f3.w);
        const int bidx = batch[node];
        const uint4* p2=(const uint4*)(g_b + (size_t)bidx*64 + s*16);
        g0=p2[0]; g1=p2[1];
      }
      *(uint4*)(drow + ((  0+base   ) ^ sw)) = ok?old0:z; *(uint4*)(drow + ((  0+base+16) ^ sw)) = ok?old1:z;
      *(uint4*)(drow + ((128+base   ) ^ sw)) = ((uint4*)t)[0]; *(uint4*)(drow + ((128+base+16) ^ sw)) = ((uint4*)t)[1];
      *(uint4*)(drow + ((256+base   ) ^ sw)) = g0; *(uint4*)(drow + ((256+base+16) ^ sw)) = g1;
    } else { // GLOB: 64 graphs
      const uint4* p0=(const uint4*)(g_b + (size_t)r*64 + s*16);
      uint4 a_=p0[0], b_=p0[1];
      const float4* p1=(const float4*)(xagg + (size_t)r*64 + s*16);
      float4 f0=p1[0], f1=p1[1], f2v=p1[2], f3=p1[3];
      u16 t[16];
      t[0]=f2b(f0.x); t[1]=f2b(f0.y); t[2]=f2b(f0.z); t[3]=f2b(f0.w);
      t[4]=f2b(f1.x); t[5]=f2b(f1.y); t[6]=f2b(f1.z); t[7]=f2b(f1.w);
      t[8]=f2b(f2v.x); t[9]=f2b(f2v.y); t[10]=f2b(f2v.z); t[11]=f2b(f2v.w);
      t[12]=f2b(f3.x); t[13]=f2b(f3.y); t[14]=f2b(f3.z); t[15]=f2b(f3.w);
      *(uint4*)(drow + ((  0+base   ) ^ sw)) = a_; *(uint4*)(drow + ((  0+base+16) ^ sw)) = b_;
      *(uint4*)(drow + ((128+base   ) ^ sw)) = ((uint4*)t)[0]; *(uint4*)(drow + ((128+base+16) ^ sw)) = ((uint4*)t)[1];
    }
  }
  __syncthreads();   // [1] gather visible

  // ---------- layer 1 (K0 -> 128) ----------
  f32x4 acc[4][2];
  #pragma unroll
  for (int rb=0;rb<4;rb++){ acc[rb][0]=f32x4{0,0,0,0}; acc[rb][1]=f32x4{0,0,0,0}; }
  #pragma unroll
  for (int kb=0;kb<KB;kb++){
    #pragma unroll
    for (int rb=0;rb<4;rb++){
      s16x8 af = *(const s16x8*)(a0 + (rb*16+lrow)*RS + ((kb*64 + aoff) ^ lsw));
      acc[rb][0] = MFMA(wA[kb][0], af, acc[rb][0]);
      acc[rb][1] = MFMA(wA[kb][1], af, acc[rb][1]);
    }
  }

  s16x8 wB[4][2];
  #pragma unroll
  for (int kb=0;kb<4;kb++){
    #pragma unroll
    for (int j=0;j<2;j++)
      wB[kb][j] = *(const s16x8*)(w2f + (size_t)(kb*8 + wave*2 + j)*64 + lane);
  }
  __syncthreads();   // [1b] all L1 reads of a0 done

  // epilogue 1 -> h1
  #pragma unroll
  for (int j=0;j<2;j++){
    const float4 bs = *(const float4*)(b1 + wave*32 + j*16 + qc);
    #pragma unroll
    for (int rb=0;rb<4;rb++){
      int row = rb*16 + lrow;
      int c2 = (wave*32 + j*16 + qc)*2;
      u16 t0=f2b(lrelu(acc[rb][j][0]+bs.x)), t1=f2b(lrelu(acc[rb][j][1]+bs.y));
      u16 t2=f2b(lrelu(acc[rb][j][2]+bs.z)), t3=f2b(lrelu(acc[rb][j][3]+bs.w));
      uint2 pk = make_uint2((u32)t0 | ((u32)t1<<16), (u32)t2 | ((u32)t3<<16));
      *(uint2*)(h1 + row*256 + (c2 ^ ((row&7)<<4))) = pk;
    }
  }
  __syncthreads();   // [2] h1 ready

  // ---------- layer 2 (128 -> 128) ----------
  f32x4 acc2[4][2];
  #pragma unroll
  for (int rb=0;rb<4;rb++){ acc2[rb][0]=f32x4{0,0,0,0}; acc2[rb][1]=f32x4{0,0,0,0}; }
  #pragma unroll
  for (int kb=0;kb<4;kb++){
    #pragma unroll
    for (int rb=0;rb<4;rb++){
      s16x8 af = *(const s16x8*)(h1 + (rb*16+lrow)*256 + ((kb*64 + aoff) ^ lsw));
      acc2[rb][0] = MFMA(wB[kb][0], af, acc2[rb][0]);
      acc2[rb][1] = MFMA(wB[kb][1], af, acc2[rb][1]);
    }
  }

  s16x8 wC[4];
  #pragma unroll
  for (int kb=0;kb<4;kb++)
    wC[kb] = *(const s16x8*)(w3f + (size_t)(kb*4 + wave)*64 + lane);

  // epilogue 2 -> h2
  #pragma unroll
  for (int j=0;j<2;j++){
    const float4 bs = *(const float4*)(b2 + wave*32 + j*16 + qc);
    #pragma unroll
    for (int rb=0;rb<4;rb++){
      int row = rb*16 + lrow;
      int c2 = (wave*32 + j*16 + qc)*2;
      u16 t0=f2b(lrelu(acc2[rb][j][0]+bs.x)), t1=f2b(lrelu(acc2[rb][j][1]+bs.y));
      u16 t2=f2b(lrelu(acc2[rb][j][2]+bs.z)), t3=f2b(lrelu(acc2[rb][j][3]+bs.w));
      uint2 pk = make_uint2((u32)t0 | ((u32)t1<<16), (u32)t2 | ((u32)t3<<16));
      *(uint2*)(h2 + row*256 + (c2 ^ ((row&7)<<4))) = pk;
    }
  }
  __syncthreads();   // [3] h2 ready

  // ---------- layer 3 (128 -> 64) ----------
  f32x4 acc3[4];
  #pragma unroll
  for (int rb=0;rb<4;rb++) acc3[rb]=f32x4{0,0,0,0};
  #pragma unroll
  for (int kb=0;kb<4;kb++){
    #pragma unroll
    for (int rb=0;rb<4;rb++){
      s16x8 af = *(const s16x8*)(h2 + (rb*16+lrow)*256 + ((kb*64 + aoff) ^ lsw));
      acc3[rb] = MFMA(wC[kb], af, acc3[rb]);
    }
  }
  {
    const float4 b3v = *(const float4*)(b3 + wave*16 + qc);
    #pragma unroll
    for (int rb=0;rb<4;rb++){
      int row = rb*16 + lrow;
      int c4 = (wave*16 + qc)*4;
      float4 o = make_float4(acc3[rb][0]+b3v.x, acc3[rb][1]+b3v.y, acc3[rb][2]+b3v.z, acc3[rb][3]+b3v.w);
      *(float4*)(h3 + row*256 + (c4 ^ ((row&7)<<4))) = o;
    }
  }
  __syncthreads();   // [4] h3 ready

  // ---------- finisher (write-only residuals) ----------
  const int r2 = tid>>2, cs = (tid&3)*16;
  const int rsw2 = (r2&7)<<4;
  if (MODE==0){
    const int slot = rowbase + r2;
    float vals[16];
    #pragma unroll
    for (int c=0;c<16;c++) vals[c]=*(const float*)(h3 + r2*256 + (((cs+c)*4)^rsw2));
    const u16* eo0=(const u16*)&old0; const u16* eo1=(const u16*)&old1;
    u16 o[16];
    #pragma unroll
    for (int c=0;c<8;c++) o[c]   = f2b(b2f(eo0[c]) + vals[c]);
    #pragma unroll
    for (int c=0;c<8;c++) o[8+c] = f2b(b2f(eo1[c]) + vals[8+c]);
    u16* p = e_b + (size_t)slot*64 + cs;
    ((uint4*)p)[0]=((uint4*)o)[0]; ((uint4*)p)[1]=((uint4*)o)[1];
    if (LAST){
      const int edge = perm[slot];
      float dwl[16];
      const float4* dw4 = (const float4*)(dw + cs);
      #pragma unroll
      for (int q=0;q<4;q++){ float4 v=dw4[q]; dwl[q*4]=v.x; dwl[q*4+1]=v.y; dwl[q*4+2]=v.z; dwl[q*4+3]=v.w; }
      float part=0.f;
      #pragma unroll
      for (int c=0;c<16;c++) part += b2f(o[c])*dwl[c];
      part += __shfl_xor(part,1);
      part += __shfl_xor(part,2);
      if ((tid&3)==0) outp[edge] = part + db[0];
    }
    // run-length-reduced segment_sum(e_new, dcol); dcol via prefetched uniform loads
    const int col64 = tid&63, rg = tid>>6;
    int gids[16];
    #pragma unroll
    for (int rr=0;rr<16;rr++) gids[rr] = dcols[rowbase + rg*16 + rr];
    float ssum = 0.f; int cur = -1;
    #pragma unroll
    for (int rr=0;rr<16;rr++){
      int row = rg*16+rr;
      int gid = gids[rr];
      float v = *(const float*)(h3 + row*256 + ((col64*4) ^ ((row&7)<<4)));
      if (gid != cur){ if (cur>=0) unsafeAtomicAdd(eagg + (size_t)cur*64 + col64, ssum); ssum=0.f; cur=gid; }
      ssum += v;
    }
    if (cur>=0) unsafeAtomicAdd(eagg + (size_t)cur*64 + col64, ssum);
  } else if (MODE==1){
    const int node = rowbase + r2;
    if (node < NN){
      float vals[16];
      #pragma unroll
      for (int c=0;c<16;c++) vals[c]=*(const float*)(h3 + r2*256 + (((cs+c)*4)^rsw2));
      const u16* xo0=(const u16*)&old0; const u16* xo1=(const u16*)&old1;
      u16 o[16];
      #pragma unroll
      for (int c=0;c<8;c++) o[c]   = f2b(b2f(xo0[c]) + vals[c]);
      #pragma unroll
      for (int c=0;c<8;c++) o[8+c] = f2b(b2f(xo1[c]) + vals[8+c]);
      u16* p = xh_b + (size_t)node*64 + cs;
      ((uint4*)p)[0]=((uint4*)o)[0]; ((uint4*)p)[1]=((uint4*)o)[1];
    }
    // per-graph reduction of x_new (batch sorted)
    const int col = tid&63, rg = tid>>6;
    int gids[16];
    #pragma unroll
    for (int rr=0;rr<16;rr++){ int nd=rowbase+rg*16+rr; gids[rr] = (nd<NN)? batch[nd] : -1; }
    float s = 0.f; int cur = -1;
    #pragma unroll
    for (int rr=0;rr<16;rr++){
      int row = rg*16+rr;
      int gid = gids[rr];
      float v = *(const float*)(h3 + row*256 + ((col*4) ^ ((row&7)<<4)));
      if (gid != cur){ if (cur>=0) unsafeAtomicAdd(xagg + cur*64 + col, s); s=0.f; cur=gid; }
      if (gid>=0) s += v;
    }
    if (cur>=0) unsafeAtomicAdd(xagg + cur*64 + col, s);
  } else {
    float vals[16];
    #pragma unroll
    for (int c=0;c<16;c++) vals[c]=*(const float*)(h3 + r2*256 + (((cs+c)*4)^rsw2));
    #pragma unroll
    for (int c=0;c<16;c++){
      int idx = r2*64 + cs + c;
      float nv = g_f[idx] + vals[c];
      g_f[idx] = nv; g_b[idx] = f2b(nv);
    }
  }
}

// ---------------- value head ----------------
__global__ void k_value(const float* __restrict__ g_f, const float* __restrict__ vw1, const float* __restrict__ vb1,
                        const float* __restrict__ vw2, const float* __restrict__ vb2, float* __restrict__ out){
  __shared__ float w1[4096];
  __shared__ float b1s[64];
  __shared__ float w2[64];
  int tid=threadIdx.x; // 64
  for (int i=tid;i<4096;i+=64) w1[i]=vw1[i];
  if (tid<64){ b1s[tid]=vb1[tid]; w2[tid]=vw2[tid]; }
  __syncthreads();
  float gi[64];
  #pragma unroll
  for (int k=0;k<64;k++) gi[k]=g_f[tid*64+k];
  float val=vb2[0];
  for (int j=0;j<64;j++){
    float s=b1s[j];
    #pragma unroll
    for (int k=0;k<64;k++) s+=gi[k]*w1[k*64+j];
    val += lrelu(s)*w2[j];
  }
  out[tid]=val;
}

extern "C" void kernel_launch(void* const* d_in, const int* in_sizes, int n_in,
                              void* d_out, int out_size, void* d_ws, size_t ws_size,
                              hipStream_t stream){
  const float* x    =(const float*)d_in[0];
  const float* ea   =(const float*)d_in[1];
  const float* uu   =(const float*)d_in[2];
  const float* eew  =(const float*)d_in[3];
  const float* eeb  =(const float*)d_in[4];
  const float* enw  =(const float*)d_in[5];
  const float* enb  =(const float*)d_in[6];
  const float* egw  =(const float*)d_in[7];
  const float* egb  =(const float*)d_in[8];
  const float* ew1  =(const float*)d_in[9];
  const float* eb1  =(const float*)d_in[10];
  const float* ew2  =(const float*)d_in[11];
  const float* eb2  =(const float*)d_in[12];
  const float* ew3  =(const float*)d_in[13];
  const float* eb3  =(const float*)d_in[14];
  const float* nw1  =(const float*)d_in[15];
  const float* nb1  =(const float*)d_in[16];
  const float* nw2  =(const float*)d_in[17];
  const float* nb2  =(const float*)d_in[18];
  const float* nw3  =(const float*)d_in[19];
  const float* nb3  =(const float*)d_in[20];
  const float* gw1  =(const float*)d_in[21];
  const float* gb1  =(const float*)d_in[22];
  const float* gw2  =(const float*)d_in[23];
  const float* gb2  =(const float*)d_in[24];
  const float* gw3  =(const float*)d_in[25];
  const float* gb3  =(const float*)d_in[26];
  const float* dw   =(const float*)d_in[27];
  const float* db   =(const float*)d_in[28];
  const float* vw1  =(const float*)d_in[29];
  const float* vb1  =(const float*)d_in[30];
  const float* vw2  =(const float*)d_in[31];
  const float* vb2  =(const float*)d_in[32];
  const int* eidx =(const int*)d_in[33];
  const int* batch=(const int*)d_in[34];

  char* ws=(char*)d_ws; size_t off=0;
  auto alloc=[&](size_t b)->char*{ char* p=ws+off; off=(off+b+255)&~(size_t)255; return p; };
  u16*   xh_b =(u16*)  alloc((size_t)NN*64*2);
  u16*   e_s  =(u16*)  alloc((size_t)EE*64*2);   // dest-sorted e features
  float* eagg =(float*)alloc((size_t)NN*64*4);
  float* xagg =(float*)alloc((size_t)BB*64*4);
  u16*   g_bb =(u16*)  alloc((size_t)BB*64*2);
  float* g_f  =(float*)alloc((size_t)BB*64*4);
  u16* ew1f=(u16*)alloc((size_t)PP*4096*16);
  u16* ew2f=(u16*)alloc((size_t)PP*2048*16);
  u16* ew3f=(u16*)alloc((size_t)PP*1024*16);
  u16* nw1f=(u16*)alloc((size_t)PP*3072*16);
  u16* nw2f=(u16*)alloc((size_t)PP*2048*16);
  u16* nw3f=(u16*)alloc((size_t)PP*1024*16);
  u16* gw1f=(u16*)alloc((size_t)PP*2048*16);
  u16* gw2f=(u16*)alloc((size_t)PP*2048*16);
  u16* gw3f=(u16*)alloc((size_t)PP*1024*16);
  int* hist  =(int*)alloc((size_t)NN*4);
  int* offs  =(int*)alloc((size_t)NN*4);
  int* perm  =(int*)alloc((size_t)EE*4);
  int* dcols =(int*)alloc((size_t)EE*4);
  int* inv   =(int*)alloc((size_t)EE*4);
  int* rows_s=(int*)alloc((size_t)EE*4);
  int* gbs   =(int*)alloc((size_t)EE*4);
  float* out=(float*)d_out;

  // ---- counting sort of edges by destination (+ gather index streams) ----
  hipMemsetAsync(hist, 0, (size_t)NN*4, stream);
  k_hist<<<(EE+255)/256,256,0,stream>>>(eidx, hist);
  k_scan<<<1,1024,0,stream>>>(hist, offs);
  k_scatter<<<(EE+255)/256,256,0,stream>>>(eidx, offs, perm, dcols, inv, rows_s, gbs, batch);

  auto rp=[&](const float* W, u16* dst, int K, int Nn){
    int total = PP*(K/32)*(Nn/16)*64;
    k_repack<<<(total+255)/256,256,0,stream>>>(W,dst,K,Nn);
  };
  rp(ew1,ew1f,256,128); rp(ew2,ew2f,128,128); rp(ew3,ew3f,128,64);
  rp(nw1,nw1f,192,128); rp(nw2,nw2f,128,128); rp(nw3,nw3f,128,64);
  rp(gw1,gw1f,128,128); rp(gw2,gw2f,128,128); rp(gw3,gw3f,128,64);

  k_embed<true ><<<(EE+255)/256,256,0,stream>>>(ea, eew, eeb, e_s, EE, inv);
  k_embed<false><<<(NN+255)/256,256,0,stream>>>(x,  enw, enb, xh_b, NN, nullptr);
  k_embed_g<<<1,64,0,stream>>>(uu, egw, egb, g_bb, g_f);

  for (int p=0;p<PP;p++){
    hipMemsetAsync(eagg, 0, (size_t)NN*64*4, stream);
    hipMemsetAsync(xagg, 0, (size_t)BB*64*4, stream);
    if (p<PP-1)
      k_mlp<256,0,false><<<EE/64,256,0,stream>>>(xh_b,e_s,eagg,xagg,g_bb,g_f,batch,perm,dcols,rows_s,gbs,
          (const uint4*)ew1f + (size_t)p*4096, (const uint4*)ew2f + (size_t)p*2048, (const uint4*)ew3f + (size_t)p*1024,
          eb1+p*128, eb2+p*128, eb3+p*64, dw, db, out);
    else
      k_mlp<256,0,true><<<EE/64,256,0,stream>>>(xh_b,e_s,eagg,xagg,g_bb,g_f,batch,perm,dcols,rows_s,gbs,
          (const uint4*)ew1f + (size_t)p*4096, (const uint4*)ew2f + (size_t)p*2048, (const uint4*)ew3f + (size_t)p*1024,
          eb1+p*128, eb2+p*128, eb3+p*64, dw, db, out);
    k_mlp<192,1,false><<<(NN+63)/64,256,0,stream>>>(xh_b,e_s,eagg,xagg,g_bb,g_f,batch,perm,dcols,rows_s,gbs,
        (const uint4*)nw1f + (size_t)p*3072, (const uint4*)nw2f + (size_t)p*2048, (const uint4*)nw3f + (size_t)p*1024,
        nb1+p*128, nb2+p*128, nb3+p*64, dw, db, out);
    k_mlp<128,2,false><<<1,256,0,stream>>>(xh_b,e_s,eagg,xagg,g_bb,g_f,batch,perm,dcols,rows_s,gbs,
        (const uint4*)gw1f + (size_t)p*2048, (const uint4*)gw2f + (size_t)p*2048, (const uint4*)gw3f + (size_t)p*1024,
        gb1+p*128, gb2+p*128, gb3+p*64, dw, db, out);
  }
  k_value<<<1,64,0,stream>>>(g_f, vw1, vb1, vw2, vb2, out+EE);
}